// Round 2
// baseline (3010.396 us; speedup 1.0000x reference)
//
#include <hip/hip_runtime.h>

// Problem constants
#define BATCH 16
#define LSEQ 1024
#define DIN 512
#define DMODEL 1024
#define D3 3072

// ---------------------------------------------------------------------------
// bfused[n] = b_in[n] + sum_k bp[k] * W_in[k][n]   (n < 3072)
// ---------------------------------------------------------------------------
__global__ void bias_fuse(const float* __restrict__ bp, const float* __restrict__ W_in,
                          const float* __restrict__ b_in, float* __restrict__ bf) {
    int n = blockIdx.x * blockDim.x + threadIdx.x;
    float s = b_in[n];
    for (int k = 0; k < DMODEL; k++) s += bp[k] * W_in[(size_t)k * D3 + n];
    bf[n] = s;
}

// ---------------------------------------------------------------------------
// Transpose k_filt [2][L][D] -> kt [2][D][L]
// ---------------------------------------------------------------------------
__global__ void transpose_k(const float* __restrict__ kf, float* __restrict__ kt) {
    __shared__ float tile[32][33];
    int s0 = blockIdx.x * 32, d0 = blockIdx.y * 32, o = blockIdx.z;
    int tx = threadIdx.x, ty = threadIdx.y;  // (32,8)
#pragma unroll
    for (int i = 0; i < 4; i++) {
        int sl = ty + 8 * i;
        tile[sl][tx] = kf[((size_t)o * LSEQ + s0 + sl) * DMODEL + d0 + tx];
    }
    __syncthreads();
#pragma unroll
    for (int i = 0; i < 4; i++) {
        int dl = ty + 8 * i;
        kt[((size_t)o * DMODEL + d0 + dl) * LSEQ + s0 + tx] = tile[tx][dl];
    }
}

// ---------------------------------------------------------------------------
// fp32 GEMM: C[M,N] = A[M,K] (row-major) * B[K,N] (row-major) + bias[N]
// 128x128 tile, BK=16, 256 threads, 8x8 microtile. bias may be null.
// ---------------------------------------------------------------------------
__global__ __launch_bounds__(256) void gemm_rm(const float* __restrict__ A,
                                               const float* __restrict__ Bw,
                                               const float* __restrict__ bias,
                                               float* __restrict__ C,
                                               int M, int N, int K) {
    __shared__ __align__(16) float As[16][132];   // k-major, padded
    __shared__ __align__(16) float Bs[16][132];
    int n0 = blockIdx.x * 128, m0 = blockIdx.y * 128;
    int tid = threadIdx.x;
    int tx = tid & 15, ty = tid >> 4;
    float acc[8][8] = {};

    for (int k0 = 0; k0 < K; k0 += 16) {
#pragma unroll
        for (int i = 0; i < 2; i++) {
            int f4 = tid + 256 * i;          // 0..511
            int row = f4 >> 2;               // 0..127
            int kq = (f4 & 3) * 4;
            float4 v = *(const float4*)&A[(size_t)(m0 + row) * K + k0 + kq];
            As[kq + 0][row] = v.x;
            As[kq + 1][row] = v.y;
            As[kq + 2][row] = v.z;
            As[kq + 3][row] = v.w;
        }
#pragma unroll
        for (int i = 0; i < 2; i++) {
            int f4 = tid + 256 * i;
            int kr = f4 >> 5;                // 0..15
            int nc = (f4 & 31) * 4;
            *(float4*)&Bs[kr][nc] = *(const float4*)&Bw[(size_t)(k0 + kr) * N + n0 + nc];
        }
        __syncthreads();
#pragma unroll 4
        for (int kk = 0; kk < 16; kk++) {
            float4 a0 = *(const float4*)&As[kk][ty * 8];
            float4 a1 = *(const float4*)&As[kk][ty * 8 + 4];
            float4 b0 = *(const float4*)&Bs[kk][tx * 8];
            float4 b1 = *(const float4*)&Bs[kk][tx * 8 + 4];
            float a[8] = {a0.x, a0.y, a0.z, a0.w, a1.x, a1.y, a1.z, a1.w};
            float b[8] = {b0.x, b0.y, b0.z, b0.w, b1.x, b1.y, b1.z, b1.w};
#pragma unroll
            for (int i = 0; i < 8; i++)
#pragma unroll
                for (int j = 0; j < 8; j++) acc[i][j] += a[i] * b[j];
        }
        __syncthreads();
    }
    float bv[8];
#pragma unroll
    for (int j = 0; j < 8; j++) bv[j] = bias ? bias[n0 + tx * 8 + j] : 0.f;
#pragma unroll
    for (int i = 0; i < 8; i++) {
        float4 c0 = {acc[i][0] + bv[0], acc[i][1] + bv[1], acc[i][2] + bv[2], acc[i][3] + bv[3]};
        float4 c1 = {acc[i][4] + bv[4], acc[i][5] + bv[5], acc[i][6] + bv[6], acc[i][7] + bv[7]};
        size_t o = (size_t)(m0 + ty * 8 + i) * N + n0 + tx * 8;
        *(float4*)&C[o] = c0;
        *(float4*)&C[o + 4] = c1;
    }
}

// ---------------------------------------------------------------------------
// fp32 GEMM with A stored transposed per batch: A[m][k] = At[b][k][t], m=b*L+t
// (K = DMODEL fixed). Same tiling as gemm_rm.
// ---------------------------------------------------------------------------
__global__ __launch_bounds__(256) void gemm_at(const float* __restrict__ At,
                                               const float* __restrict__ Bw,
                                               const float* __restrict__ bias,
                                               float* __restrict__ C, int N) {
    __shared__ __align__(16) float As[16][132];
    __shared__ __align__(16) float Bs[16][132];
    int n0 = blockIdx.x * 128, m0 = blockIdx.y * 128;
    int b = m0 >> 10;
    int t0 = m0 & 1023;
    int tid = threadIdx.x;
    int tx = tid & 15, ty = tid >> 4;
    float acc[8][8] = {};

    for (int k0 = 0; k0 < DMODEL; k0 += 16) {
#pragma unroll
        for (int i = 0; i < 2; i++) {
            int f4 = tid + 256 * i;
            int kr = f4 >> 5;                // 0..15
            int mc = (f4 & 31) * 4;
            *(float4*)&As[kr][mc] =
                *(const float4*)&At[((size_t)b * DMODEL + k0 + kr) * LSEQ + t0 + mc];
        }
#pragma unroll
        for (int i = 0; i < 2; i++) {
            int f4 = tid + 256 * i;
            int kr = f4 >> 5;
            int nc = (f4 & 31) * 4;
            *(float4*)&Bs[kr][nc] = *(const float4*)&Bw[(size_t)(k0 + kr) * N + n0 + nc];
        }
        __syncthreads();
#pragma unroll 4
        for (int kk = 0; kk < 16; kk++) {
            float4 a0 = *(const float4*)&As[kk][ty * 8];
            float4 a1 = *(const float4*)&As[kk][ty * 8 + 4];
            float4 b0 = *(const float4*)&Bs[kk][tx * 8];
            float4 b1 = *(const float4*)&Bs[kk][tx * 8 + 4];
            float a[8] = {a0.x, a0.y, a0.z, a0.w, a1.x, a1.y, a1.z, a1.w};
            float b[8] = {b0.x, b0.y, b0.z, b0.w, b1.x, b1.y, b1.z, b1.w};
#pragma unroll
            for (int i = 0; i < 8; i++)
#pragma unroll
                for (int j = 0; j < 8; j++) acc[i][j] += a[i] * b[j];
        }
        __syncthreads();
    }
    float bv[8];
#pragma unroll
    for (int j = 0; j < 8; j++) bv[j] = bias[n0 + tx * 8 + j];
#pragma unroll
    for (int i = 0; i < 8; i++) {
        float4 c0 = {acc[i][0] + bv[0], acc[i][1] + bv[1], acc[i][2] + bv[2], acc[i][3] + bv[3]};
        float4 c1 = {acc[i][4] + bv[4], acc[i][5] + bv[5], acc[i][6] + bv[6], acc[i][7] + bv[7]};
        size_t o = (size_t)(m0 + ty * 8 + i) * N + n0 + tx * 8;
        *(float4*)&C[o] = c0;
        *(float4*)&C[o + 4] = c1;
    }
}

// ---------------------------------------------------------------------------
// Depthwise causal 3-tap conv on UC [c,L,3D] + gating.
// Writes At[bl][d][t] = v*x2 and X1t[bl][d][t] = x1 (transposed layout).
// grid (L/32, D/32, c), block (32,8)
// ---------------------------------------------------------------------------
__global__ __launch_bounds__(256) void shortconv_gate(const float* __restrict__ UC,
                                                      const float* __restrict__ sw,
                                                      const float* __restrict__ sb,
                                                      float* __restrict__ At,
                                                      float* __restrict__ X1t) {
    __shared__ float tin[34][33];
    __shared__ float outA[32][33];
    __shared__ float outX[32][33];
    int t0 = blockIdx.x * 32, c0 = blockIdx.y * 32, b = blockIdx.z;
    int tx = threadIdx.x, ty = threadIdx.y;
    float res[3][4];
#pragma unroll
    for (int g = 0; g < 3; g++) {
        int ch = g * DMODEL + c0 + tx;
        __syncthreads();  // protect tin reuse across g
        for (int r = ty; r < 34; r += 8) {
            int t = t0 + r - 2;
            tin[r][tx] = (t >= 0) ? UC[((size_t)b * LSEQ + t) * D3 + ch] : 0.f;
        }
        __syncthreads();
        float w0 = sw[ch * 3 + 0], w1 = sw[ch * 3 + 1], w2 = sw[ch * 3 + 2], bb = sb[ch];
#pragma unroll
        for (int i = 0; i < 4; i++) {
            int r = ty + 8 * i + 2;
            res[g][i] = w0 * tin[r - 2][tx] + w1 * tin[r - 1][tx] + w2 * tin[r][tx] + bb;
        }
    }
#pragma unroll
    for (int i = 0; i < 4; i++) {
        outA[tx][ty + 8 * i] = res[2][i] * res[1][i];  // v * x2, indexed [c][t]
        outX[tx][ty + 8 * i] = res[0][i];              // x1
    }
    __syncthreads();
#pragma unroll
    for (int i = 0; i < 4; i++) {
        int cl = ty + 8 * i;
        size_t o = ((size_t)b * DMODEL + c0 + cl) * LSEQ + t0 + tx;
        At[o] = outA[cl][tx];
        X1t[o] = outX[cl][tx];
    }
}

// ---------------------------------------------------------------------------
// Long causal conv per (b,d): y[t] = sum_{s<=t} k[s]*a[t-s]  (+ a*Dbias) (* gate)
// in_t/out_t/gate: [c][D][L]; kt: [D][L]. In-place safe (out_t may == in_t):
// the block exclusively owns its row and fully stages it before writing.
// ---------------------------------------------------------------------------
__global__ __launch_bounds__(256) void conv_long(const float* __restrict__ in_t,
                                                 const float* __restrict__ kt,
                                                 const float* __restrict__ Dbias,
                                                 const float* __restrict__ gate,
                                                 float* __restrict__ out_t) {
    __shared__ __align__(16) float sa[1024];
    __shared__ __align__(16) float skp[1032];  // skp[7+j] = k[j], zero-padded ends
    int bd = blockIdx.x;
    int d = bd & (DMODEL - 1);
    int tid = threadIdx.x;
    size_t base = (size_t)bd * LSEQ;

    *(float4*)&sa[4 * tid] = *(const float4*)&in_t[base + 4 * tid];
    float4 vk = *(const float4*)&kt[(size_t)d * LSEQ + 4 * tid];
    skp[7 + 4 * tid + 0] = vk.x;
    skp[7 + 4 * tid + 1] = vk.y;
    skp[7 + 4 * tid + 2] = vk.z;
    skp[7 + 4 * tid + 3] = vk.w;
    if (tid < 7) skp[tid] = 0.f;
    if (tid == 7) skp[1031] = 0.f;
    __syncthreads();

    int t0 = 4 * tid;
    float acc0 = 0.f, acc1 = 0.f, acc2 = 0.f, acc3 = 0.f;
    for (int s0 = 0; s0 <= t0; s0 += 4) {
        float4 av = *(const float4*)&sa[s0];
        float4 wa = *(const float4*)&skp[t0 - s0 + 4];  // k[t0-s0-3 .. t0-s0]
        float4 wb = *(const float4*)&skp[t0 - s0 + 8];  // k[t0-s0+1 .. t0-s0+4]
        acc0 += av.x * wa.w + av.y * wa.z + av.z * wa.y + av.w * wa.x;
        acc1 += av.x * wb.x + av.y * wa.w + av.z * wa.z + av.w * wa.y;
        acc2 += av.x * wb.y + av.y * wb.x + av.z * wa.w + av.w * wa.z;
        acc3 += av.x * wb.z + av.y * wb.y + av.z * wb.x + av.w * wa.w;
    }
    float db = Dbias[d];
    float4 vin = *(const float4*)&sa[t0];
    float4 y = {acc0 + vin.x * db, acc1 + vin.y * db, acc2 + vin.z * db, acc3 + vin.w * db};
    if (gate) {
        float4 gv = *(const float4*)&gate[base + t0];
        y.x *= gv.x; y.y *= gv.y; y.z *= gv.z; y.w *= gv.w;
    }
    *(float4*)&out_t[base + t0] = y;
}

// ---------------------------------------------------------------------------
extern "C" void kernel_launch(void* const* d_in, const int* in_sizes, int n_in,
                              void* d_out, int out_size, void* d_ws, size_t ws_size,
                              hipStream_t stream) {
    (void)in_sizes; (void)n_in; (void)out_size;
    const float* x    = (const float*)d_in[0];
    const float* Wp   = (const float*)d_in[1];
    const float* bp   = (const float*)d_in[2];
    const float* W_in = (const float*)d_in[3];
    const float* b_in = (const float*)d_in[4];
    const float* sw   = (const float*)d_in[5];
    const float* sb   = (const float*)d_in[6];
    const float* kf   = (const float*)d_in[7];
    const float* Db   = (const float*)d_in[8];
    const float* Wout = (const float*)d_in[9];
    const float* bout = (const float*)d_in[10];
    float* out = (float*)d_out;

    // Persistent workspace region
    char* ws = (char*)d_ws;
    const size_t WF_B = (size_t)DIN * D3 * 4;         //  6,291,456
    const size_t BF_B = 16384;                        //  3072*4 padded
    const size_t KT_B = (size_t)2 * DMODEL * LSEQ * 4;//  8,388,608
    float* Wf = (float*)ws;
    float* bf = (float*)(ws + WF_B);
    float* kt = (float*)(ws + WF_B + BF_B);
    const size_t persist = WF_B + BF_B + KT_B;        // ~14.7 MB

    // Per-batch chunk footprint: UC (L*3D) + At (D*L) + X1t (D*L) floats
    const size_t UC_B_PER  = (size_t)LSEQ * D3 * 4;     // 12,582,912
    const size_t ROW_B_PER = (size_t)DMODEL * LSEQ * 4; //  4,194,304
    const size_t per_batch = UC_B_PER + 2 * ROW_B_PER;  // 20,971,520
    int c = 16;
    while (c > 1 && persist + (size_t)c * per_batch > ws_size) c >>= 1;

    float* UC  = (float*)(ws + persist);
    float* At  = (float*)(ws + persist + (size_t)c * UC_B_PER);
    float* X1t = (float*)(ws + persist + (size_t)c * UC_B_PER + (size_t)c * ROW_B_PER);

    // One-time (per call) weight prep
    bias_fuse<<<D3 / 256, 256, 0, stream>>>(bp, W_in, b_in, bf);
    gemm_rm<<<dim3(D3 / 128, DIN / 128), 256, 0, stream>>>(Wp, W_in, nullptr, Wf,
                                                           DIN, D3, DMODEL);
    transpose_k<<<dim3(32, 32, 2), dim3(32, 8), 0, stream>>>(kf, kt);

    for (int b0 = 0; b0 < BATCH; b0 += c) {
        const float* xb = x + (size_t)b0 * LSEQ * DIN;
        // u = x @ Wf + bf   -> UC [c,L,3D]
        gemm_rm<<<dim3(D3 / 128, c * LSEQ / 128), 256, 0, stream>>>(
            xb, Wf, bf, UC, c * LSEQ, D3, DIN);
        // short conv + split + gate (v*x2), transposed outputs
        shortconv_gate<<<dim3(LSEQ / 32, DMODEL / 32, c), dim3(32, 8), 0, stream>>>(
            UC, sw, sb, At, X1t);
        // v1 = (conv(A,k0) + A*D0) * x1   (in-place on At)
        conv_long<<<c * DMODEL, 256, 0, stream>>>(At, kt, Db, X1t, At);
        // v2 = conv(v1,k1) + v1*D1        (in-place on At)
        conv_long<<<c * DMODEL, 256, 0, stream>>>(At, kt + (size_t)DMODEL * LSEQ,
                                                  Db + DMODEL, nullptr, At);
        // out rows = v2 @ W_out + b_out
        gemm_at<<<dim3(DMODEL / 128, c * LSEQ / 128), 256, 0, stream>>>(
            At, Wout, bout, out + (size_t)b0 * LSEQ * DMODEL, DMODEL);
    }
}

// Round 3
// 1212.104 us; speedup vs baseline: 2.4836x; 2.4836x over previous
//
#include <hip/hip_runtime.h>

// Problem constants
#define BATCH 16
#define LSEQ 1024
#define DIN 512
#define DMODEL 1024
#define D3 3072

typedef __attribute__((ext_vector_type(4))) float f32x4;
typedef __attribute__((ext_vector_type(8))) short bf16x8;

static __device__ __forceinline__ ushort f2bf(float f) {
    uint u = __float_as_uint(f);
    return (ushort)((u + 0x7FFFu + ((u >> 16) & 1u)) >> 16);
}

#define GLD16(ldst, gsrc)                                                        \
    __builtin_amdgcn_global_load_lds(                                            \
        (const __attribute__((address_space(1))) void*)(gsrc),                   \
        (__attribute__((address_space(3))) void*)(ldst), 16, 0, 0)

// ---------------------------------------------------------------------------
// bf16 MFMA GEMM: C[M,N] = A[M,K]bf16 * B[K,N] (given as Bt[N,K]bf16) + bias.
// 128x128 tile, BK=32, 256 threads (4 waves), 4x4 16x16x32 frags per wave.
// ---------------------------------------------------------------------------
template <typename OutT, bool HAS_BIAS>
__global__ __launch_bounds__(256) void gemm_mfma(const ushort* __restrict__ A,
                                                 const ushort* __restrict__ Bt,
                                                 const float* __restrict__ bias,
                                                 OutT* __restrict__ C,
                                                 int M, int N, int K) {
    __shared__ ushort Als[128 * 32];
    __shared__ ushort Bls[128 * 32];
    int n0 = blockIdx.x * 128, m0 = blockIdx.y * 128;
    int t = threadIdx.x;
    int w = t >> 6, l = t & 63;
    int wm = w & 1, wn = w >> 1;
    f32x4 acc[4][4] = {};

    int rowA = t >> 2;                 // 0..63
    int kb = (t & 3) * 8;              // ushort offset within 32-wide k slab
    const ushort* gA0 = A + (size_t)(m0 + rowA) * K + kb;
    const ushort* gA1 = gA0 + (size_t)64 * K;
    const ushort* gB0 = Bt + (size_t)(n0 + rowA) * K + kb;
    const ushort* gB1 = gB0 + (size_t)64 * K;
    ushort* lA0 = Als + 512 * w;       // wave-uniform LDS bases
    ushort* lA1 = Als + 2048 + 512 * w;
    ushort* lB0 = Bls + 512 * w;
    ushort* lB1 = Bls + 2048 + 512 * w;

    int aoff = (wm * 64 + (l & 15)) * 32 + (l >> 4) * 8;
    int boff = (wn * 64 + (l & 15)) * 32 + (l >> 4) * 8;

    for (int k0 = 0; k0 < K; k0 += 32) {
        GLD16(lA0, gA0 + k0);
        GLD16(lA1, gA1 + k0);
        GLD16(lB0, gB0 + k0);
        GLD16(lB1, gB1 + k0);
        __syncthreads();
        bf16x8 af[4], bg[4];
#pragma unroll
        for (int i = 0; i < 4; i++) af[i] = *(const bf16x8*)&Als[aoff + i * 512];
#pragma unroll
        for (int j = 0; j < 4; j++) bg[j] = *(const bf16x8*)&Bls[boff + j * 512];
#pragma unroll
        for (int i = 0; i < 4; i++)
#pragma unroll
            for (int j = 0; j < 4; j++)
                acc[i][j] = __builtin_amdgcn_mfma_f32_16x16x32_bf16(af[i], bg[j],
                                                                    acc[i][j], 0, 0, 0);
        __syncthreads();
    }

#pragma unroll
    for (int j = 0; j < 4; j++) {
        int col = n0 + wn * 64 + 16 * j + (l & 15);
        float bv = HAS_BIAS ? bias[col] : 0.f;
#pragma unroll
        for (int i = 0; i < 4; i++) {
            int row0 = m0 + wm * 64 + 16 * i + (l >> 4) * 4;
#pragma unroll
            for (int r = 0; r < 4; r++) {
                float v = acc[i][j][r] + bv;
                if constexpr (sizeof(OutT) == 2)
                    C[(size_t)(row0 + r) * N + col] = (OutT)f2bf(v);
                else
                    C[(size_t)(row0 + r) * N + col] = (OutT)v;
            }
        }
    }
}

// ---------------------------------------------------------------------------
// Flat fp32 -> bf16 convert (4 elems/thread)
// ---------------------------------------------------------------------------
__global__ void cvt_bf16(const float* __restrict__ in, ushort* __restrict__ out, int n4) {
    int i = blockIdx.x * blockDim.x + threadIdx.x;
    if (i >= n4) return;
    float4 v = *(const float4*)&in[4 * i];
    uint2 p;
    p.x = (uint)f2bf(v.x) | ((uint)f2bf(v.y) << 16);
    p.y = (uint)f2bf(v.z) | ((uint)f2bf(v.w) << 16);
    *(uint2*)&out[4 * i] = p;
}

// ---------------------------------------------------------------------------
// Transpose + convert: in [z][R][C] fp32 -> out [z][C][R] bf16
// grid (C/32, R/32, Z), block (32,8)
// ---------------------------------------------------------------------------
__global__ void transpose_cvt(const float* __restrict__ in, ushort* __restrict__ out,
                              int R, int C, size_t in_z, size_t out_z) {
    __shared__ float tile[32][33];
    int c0 = blockIdx.x * 32, r0 = blockIdx.y * 32, z = blockIdx.z;
    int tx = threadIdx.x, ty = threadIdx.y;
    const float* ip = in + (size_t)z * in_z;
    ushort* op = out + (size_t)z * out_z;
#pragma unroll
    for (int i = 0; i < 4; i++)
        tile[ty + 8 * i][tx] = ip[(size_t)(r0 + ty + 8 * i) * C + c0 + tx];
    __syncthreads();
#pragma unroll
    for (int i = 0; i < 4; i++)
        op[(size_t)(c0 + ty + 8 * i) * R + r0 + tx] = f2bf(tile[tx][ty + 8 * i]);
}

// ---------------------------------------------------------------------------
// bfused[n] = b_in[n] + sum_k bp[k] * W_in[k][n]
// ---------------------------------------------------------------------------
__global__ void bias_fuse(const float* __restrict__ bp, const float* __restrict__ W_in,
                          const float* __restrict__ b_in, float* __restrict__ bf) {
    int n = blockIdx.x * blockDim.x + threadIdx.x;
    float s = b_in[n];
    for (int k = 0; k < DMODEL; k++) s += bp[k] * W_in[(size_t)k * D3 + n];
    bf[n] = s;
}

// ---------------------------------------------------------------------------
// Transpose k_filt [2][L][D] fp32 -> kt [2][D][L] fp32
// ---------------------------------------------------------------------------
__global__ void transpose_k(const float* __restrict__ kf, float* __restrict__ kt) {
    __shared__ float tile[32][33];
    int s0 = blockIdx.x * 32, d0 = blockIdx.y * 32, o = blockIdx.z;
    int tx = threadIdx.x, ty = threadIdx.y;
#pragma unroll
    for (int i = 0; i < 4; i++)
        tile[ty + 8 * i][tx] = kf[((size_t)o * LSEQ + s0 + ty + 8 * i) * DMODEL + d0 + tx];
    __syncthreads();
#pragma unroll
    for (int i = 0; i < 4; i++)
        kt[((size_t)o * DMODEL + d0 + ty + 8 * i) * LSEQ + s0 + tx] = tile[tx][ty + 8 * i];
}

// ---------------------------------------------------------------------------
// Depthwise causal 3-tap conv on UC [c,L,3D] + gating.
// At[bl][d][t] = v*x2, X1t[bl][d][t] = x1. grid (L/32, D/32, c), block (32,8)
// ---------------------------------------------------------------------------
__global__ __launch_bounds__(256) void shortconv_gate(const float* __restrict__ UC,
                                                      const float* __restrict__ sw,
                                                      const float* __restrict__ sb,
                                                      float* __restrict__ At,
                                                      float* __restrict__ X1t) {
    __shared__ float tin[34][33];
    __shared__ float outA[32][33];
    __shared__ float outX[32][33];
    int t0 = blockIdx.x * 32, c0 = blockIdx.y * 32, b = blockIdx.z;
    int tx = threadIdx.x, ty = threadIdx.y;
    float res[3][4];
#pragma unroll
    for (int g = 0; g < 3; g++) {
        int ch = g * DMODEL + c0 + tx;
        __syncthreads();
        for (int r = ty; r < 34; r += 8) {
            int t = t0 + r - 2;
            tin[r][tx] = (t >= 0) ? UC[((size_t)b * LSEQ + t) * D3 + ch] : 0.f;
        }
        __syncthreads();
        float w0 = sw[ch * 3 + 0], w1 = sw[ch * 3 + 1], w2 = sw[ch * 3 + 2], bb = sb[ch];
#pragma unroll
        for (int i = 0; i < 4; i++) {
            int r = ty + 8 * i + 2;
            res[g][i] = w0 * tin[r - 2][tx] + w1 * tin[r - 1][tx] + w2 * tin[r][tx] + bb;
        }
    }
#pragma unroll
    for (int i = 0; i < 4; i++) {
        outA[tx][ty + 8 * i] = res[2][i] * res[1][i];
        outX[tx][ty + 8 * i] = res[0][i];
    }
    __syncthreads();
#pragma unroll
    for (int i = 0; i < 4; i++) {
        int cl = ty + 8 * i;
        size_t o = ((size_t)b * DMODEL + c0 + cl) * LSEQ + t0 + tx;
        At[o] = outA[cl][tx];
        X1t[o] = outX[cl][tx];
    }
}

// ---------------------------------------------------------------------------
// 4-output sliding-window causal conv segment: y[t0..t0+3] over s in [0,t0]
// skp[7+j] = k[j] (zero-padded both ends)
// ---------------------------------------------------------------------------
static __device__ __forceinline__ f32x4 conv4(const float* sa, const float* skp, int t0) {
    float a0 = 0.f, a1 = 0.f, a2 = 0.f, a3 = 0.f;
    float4 wa = *(const float4*)&skp[4];  // k[-3..0]
    for (int s0 = t0; s0 >= 0; s0 -= 4) {
        float4 av = *(const float4*)&sa[s0];
        float4 wb = *(const float4*)&skp[t0 - s0 + 8];  // k[o+1..o+4]
        a0 += av.x * wa.w + av.y * wa.z + av.z * wa.y + av.w * wa.x;
        a1 += av.x * wb.x + av.y * wa.w + av.z * wa.z + av.w * wa.y;
        a2 += av.x * wb.y + av.y * wb.x + av.z * wa.w + av.w * wa.z;
        a3 += av.x * wb.z + av.y * wb.y + av.z * wb.x + av.w * wa.w;
        wa = wb;
    }
    return f32x4{a0, a1, a2, a3};
}

// ---------------------------------------------------------------------------
// Long causal conv: 2 batch-rows per block (shared k), 128 threads/row.
// Each thread: symmetric output pair (4*lt, 1020-4*lt) -> uniform trip count.
// In-place safe. grid = ceil(nb/2)*1024 blocks.
// ---------------------------------------------------------------------------
__global__ __launch_bounds__(256) void conv_long2(const float* __restrict__ in_t,
                                                  const float* __restrict__ kt,
                                                  const float* __restrict__ Dbias,
                                                  const float* __restrict__ gate,
                                                  float* __restrict__ out_t, int nb) {
    __shared__ __align__(16) float sa[2][1024];
    __shared__ __align__(16) float skp[1040];
    int blk = blockIdx.x;
    int d = blk & (DMODEL - 1);
    int b0 = (blk >> 10) * 2;
    int tid = threadIdx.x;
    int row = tid >> 7, lt = tid & 127;
    bool live = (b0 + row) < nb;
    size_t base = ((size_t)(b0 + row) * DMODEL + d) * LSEQ;

    {
        float4 vk = *(const float4*)&kt[(size_t)d * LSEQ + 4 * tid];
        skp[7 + 4 * tid] = vk.x;
        skp[8 + 4 * tid] = vk.y;
        skp[9 + 4 * tid] = vk.z;
        skp[10 + 4 * tid] = vk.w;
    }
    if (tid < 7) skp[tid] = 0.f;
    if (tid >= 16 && tid < 25) skp[1015 + tid] = 0.f;  // skp[1031..1039]
    if (live) {
        *(float4*)&sa[row][8 * lt] = *(const float4*)&in_t[base + 8 * lt];
        *(float4*)&sa[row][8 * lt + 4] = *(const float4*)&in_t[base + 8 * lt + 4];
    }
    __syncthreads();

    int tLo = 4 * lt;
    int tHi = 1020 - 4 * lt;
    f32x4 yLo = conv4(sa[row], skp, tLo);
    f32x4 yHi = conv4(sa[row], skp, tHi);
    float db = Dbias[d];
    float4 vLo = *(const float4*)&sa[row][tLo];
    float4 vHi = *(const float4*)&sa[row][tHi];
    float4 oLo = {yLo.x + vLo.x * db, yLo.y + vLo.y * db, yLo.z + vLo.z * db, yLo.w + vLo.w * db};
    float4 oHi = {yHi.x + vHi.x * db, yHi.y + vHi.y * db, yHi.z + vHi.z * db, yHi.w + vHi.w * db};
    if (gate) {
        float4 gLo = *(const float4*)&gate[base + tLo];
        float4 gHi = *(const float4*)&gate[base + tHi];
        oLo.x *= gLo.x; oLo.y *= gLo.y; oLo.z *= gLo.z; oLo.w *= gLo.w;
        oHi.x *= gHi.x; oHi.y *= gHi.y; oHi.z *= gHi.z; oHi.w *= gHi.w;
    }
    if (live) {
        *(float4*)&out_t[base + tLo] = oLo;
        *(float4*)&out_t[base + tHi] = oHi;
    }
}

// ---------------------------------------------------------------------------
extern "C" void kernel_launch(void* const* d_in, const int* in_sizes, int n_in,
                              void* d_out, int out_size, void* d_ws, size_t ws_size,
                              hipStream_t stream) {
    (void)in_sizes; (void)n_in; (void)out_size;
    const float* x    = (const float*)d_in[0];
    const float* Wp   = (const float*)d_in[1];
    const float* bp   = (const float*)d_in[2];
    const float* W_in = (const float*)d_in[3];
    const float* b_in = (const float*)d_in[4];
    const float* sw   = (const float*)d_in[5];
    const float* sb   = (const float*)d_in[6];
    const float* kf   = (const float*)d_in[7];
    const float* Db   = (const float*)d_in[8];
    const float* Wout = (const float*)d_in[9];
    const float* bout = (const float*)d_in[10];
    float* out = (float*)d_out;

    char* ws = (char*)d_ws;
    // Persistent: Wf_t(3,145,728) bf(16,384) kt(8,388,608) Wout_t(2,097,152)
    ushort* Wf_t   = (ushort*)(ws);
    float*  bf     = (float*)(ws + 3145728);
    float*  kt     = (float*)(ws + 3162112);
    ushort* Wout_t = (ushort*)(ws + 11550720);
    const size_t SCR = 13647872;
    // Prep scratch (aliased with chunk region; rewritten every call before use)
    ushort* W_inT = (ushort*)(ws + SCR);
    ushort* Wp_bf = (ushort*)(ws + SCR + 6291456);

    // Chunk sizing
    const size_t UC_B  = 12582912;  // per batch: 1024*3072*4
    const size_t ROW_B = 4194304;   // per batch: 1024*1024*4
    const size_t V2_B  = 2097152;   // per batch: 1024*1024*2
    const size_t XB_B  = 1048576;   // per batch: 1024*512*2
    const size_t per_batch = UC_B + 2 * ROW_B + V2_B + XB_B;  // 24,117,248
    int c = 16;
    while (c > 1 && SCR + (size_t)c * per_batch > ws_size) c >>= 1;

    float*  UC   = (float*)(ws + SCR);
    float*  At   = (float*)(ws + SCR + (size_t)c * UC_B);
    float*  X1t  = (float*)(ws + SCR + (size_t)c * (UC_B + ROW_B));
    ushort* V2bf = (ushort*)(ws + SCR + (size_t)c * (UC_B + 2 * ROW_B));
    ushort* x_bf = (ushort*)(ws + SCR + (size_t)c * (UC_B + 2 * ROW_B + V2_B));

    // ---- one-time prep ----
    // W_inT bf16 [3072][1024], Wp_bf bf16 [512][1024]
    transpose_cvt<<<dim3(96, 32, 1), dim3(32, 8), 0, stream>>>(W_in, W_inT, DMODEL, D3, 0, 0);
    cvt_bf16<<<512, 256, 0, stream>>>(Wp, Wp_bf, DIN * DMODEL / 4);
    // Wf_t[n][k] = sum_j W_in[j][n] * Wp[k][j]  (M=3072,N=512,K=1024)
    gemm_mfma<ushort, false><<<dim3(4, 24), 256, 0, stream>>>(W_inT, Wp_bf, nullptr,
                                                              Wf_t, D3, DIN, DMODEL);
    bias_fuse<<<D3 / 256, 256, 0, stream>>>(bp, W_in, b_in, bf);
    transpose_cvt<<<dim3(32, 32, 1), dim3(32, 8), 0, stream>>>(Wout, Wout_t, DMODEL, DMODEL, 0, 0);
    transpose_k<<<dim3(32, 32, 2), dim3(32, 8), 0, stream>>>(kf, kt);

    // ---- batch chunks ----
    for (int b0 = 0; b0 < BATCH; b0 += c) {
        // x chunk -> bf16
        cvt_bf16<<<c * 512, 256, 0, stream>>>(x + (size_t)b0 * LSEQ * DIN, x_bf,
                                              c * LSEQ * DIN / 4);
        // UC = x_bf @ Wf + bf   [cL, 3072]
        gemm_mfma<float, true><<<dim3(24, c * 8), 256, 0, stream>>>(
            x_bf, Wf_t, bf, UC, c * LSEQ, D3, DIN);
        // short conv + split + gate (v*x2) -> transposed At, X1t
        shortconv_gate<<<dim3(32, 32, c), dim3(32, 8), 0, stream>>>(UC, sw, sb, At, X1t);
        // v1 = (conv(A,k0) + A*D0) * x1   (in-place)
        conv_long2<<<((c + 1) / 2) * 1024, 256, 0, stream>>>(At, kt, Db, X1t, At, c);
        // v2 = conv(v1,k1) + v1*D1        (in-place)
        conv_long2<<<((c + 1) / 2) * 1024, 256, 0, stream>>>(
            At, kt + (size_t)DMODEL * LSEQ, Db + DMODEL, nullptr, At, c);
        // V2bf [c][L][D] bf16 <- transpose At [c][D][L]
        transpose_cvt<<<dim3(32, 32, c), dim3(32, 8), 0, stream>>>(
            At, V2bf, DMODEL, LSEQ, (size_t)DMODEL * LSEQ, (size_t)LSEQ * DMODEL);
        // out = V2 @ W_out + b_out
        gemm_mfma<float, true><<<dim3(8, c * 8), 256, 0, stream>>>(
            V2bf, Wout_t, bout, out + (size_t)b0 * LSEQ * DMODEL, c * LSEQ, DMODEL, DMODEL);
    }
}

// Round 5
// 557.372 us; speedup vs baseline: 5.4011x; 2.1747x over previous
//
#include <hip/hip_runtime.h>

#define BATCH 16
#define LSEQ 1024
#define DIN 512
#define DMODEL 1024
#define D3 3072
#define KCP 1064  // padded stride of each reversed-k copy (2128B: all 8 copies distinct 16B phase mod 128B)

typedef __attribute__((ext_vector_type(4))) float f32x4;
typedef __attribute__((ext_vector_type(8))) short bf16x8;

static __device__ __forceinline__ ushort f2bf(float f) {
    uint u = __float_as_uint(f);
    return (ushort)((u + 0x7FFFu + ((u >> 16) & 1u)) >> 16);
}
static __device__ __forceinline__ float bf2f(ushort h) {
    return __uint_as_float(((uint)h) << 16);
}

#define GLD16(ldst, gsrc)                                                        \
    __builtin_amdgcn_global_load_lds(                                            \
        (const __attribute__((address_space(1))) void*)(gsrc),                   \
        (__attribute__((address_space(3))) void*)(ldst), 16, 0, 0)

// ---------------------------------------------------------------------------
// bf16 MFMA GEMM: C[M,N] = A[M,K]bf16 * B (as Bt[N,K]bf16) + bias.
// 128x128 tile, BK=32, 256 threads (4 waves), 4x4 16x16x32 frags per wave.
// ---------------------------------------------------------------------------
template <typename OutT, bool HAS_BIAS>
__global__ __launch_bounds__(256) void gemm_mfma(const ushort* __restrict__ A,
                                                 const ushort* __restrict__ Bt,
                                                 const float* __restrict__ bias,
                                                 OutT* __restrict__ C,
                                                 int M, int N, int K) {
    __shared__ ushort Als[128 * 32];
    __shared__ ushort Bls[128 * 32];
    int n0 = blockIdx.x * 128, m0 = blockIdx.y * 128;
    int t = threadIdx.x;
    int w = t >> 6, l = t & 63;
    int wm = w & 1, wn = w >> 1;
    f32x4 acc[4][4] = {};

    int rowA = t >> 2;
    int kb = (t & 3) * 8;
    const ushort* gA0 = A + (size_t)(m0 + rowA) * K + kb;
    const ushort* gA1 = gA0 + (size_t)64 * K;
    const ushort* gB0 = Bt + (size_t)(n0 + rowA) * K + kb;
    const ushort* gB1 = gB0 + (size_t)64 * K;
    ushort* lA0 = Als + 512 * w;
    ushort* lA1 = Als + 2048 + 512 * w;
    ushort* lB0 = Bls + 512 * w;
    ushort* lB1 = Bls + 2048 + 512 * w;

    int aoff = (wm * 64 + (l & 15)) * 32 + (l >> 4) * 8;
    int boff = (wn * 64 + (l & 15)) * 32 + (l >> 4) * 8;

    for (int k0 = 0; k0 < K; k0 += 32) {
        GLD16(lA0, gA0 + k0);
        GLD16(lA1, gA1 + k0);
        GLD16(lB0, gB0 + k0);
        GLD16(lB1, gB1 + k0);
        __syncthreads();
        bf16x8 af[4], bg[4];
#pragma unroll
        for (int i = 0; i < 4; i++) af[i] = *(const bf16x8*)&Als[aoff + i * 512];
#pragma unroll
        for (int j = 0; j < 4; j++) bg[j] = *(const bf16x8*)&Bls[boff + j * 512];
#pragma unroll
        for (int i = 0; i < 4; i++)
#pragma unroll
            for (int j = 0; j < 4; j++)
                acc[i][j] = __builtin_amdgcn_mfma_f32_16x16x32_bf16(af[i], bg[j],
                                                                    acc[i][j], 0, 0, 0);
        __syncthreads();
    }

#pragma unroll
    for (int j = 0; j < 4; j++) {
        int col = n0 + wn * 64 + 16 * j + (l & 15);
        float bv = HAS_BIAS ? bias[col] : 0.f;
#pragma unroll
        for (int i = 0; i < 4; i++) {
            int row0 = m0 + wm * 64 + 16 * i + (l >> 4) * 4;
#pragma unroll
            for (int r = 0; r < 4; r++) {
                float v = acc[i][j][r] + bv;
                if constexpr (sizeof(OutT) == 2)
                    C[(size_t)(row0 + r) * N + col] = (OutT)f2bf(v);
                else
                    C[(size_t)(row0 + r) * N + col] = (OutT)v;
            }
        }
    }
}

// ---------------------------------------------------------------------------
// Fused long-conv pair via block-Toeplitz MFMA, one workgroup per channel d.
// a(=v*x2) in LDS (bf16, XOR-swizzled); 8 parity-shifted reversed-k copies
// give aligned ds_read_b128 B-fragments: T_m[q][tr] = k[32m+tr-q].
// pass0: y1 = conv_k0(a) + a*D0;  a <- y1 * x1
// pass1: y2 = conv_k1(a) + a*D1;  write V2t[b][d][t] bf16
// ---------------------------------------------------------------------------
__global__ __launch_bounds__(512, 4) void conv_mfma(const ushort* __restrict__ At,
                                                    const ushort* __restrict__ X1t,
                                                    const float* __restrict__ kt,
                                                    const float* __restrict__ Db,
                                                    ushort* __restrict__ V2t, int nb) {
    __shared__ ushort a_lds[16 * 1024];   // 32 KB
    __shared__ ushort kc[2 * 8 * KCP];    // 34 KB
    int d = blockIdx.x;
    int tid = threadIdx.x;
    int w = tid >> 6, l = tid & 63;
    int lr = l & 15, lq = l >> 4;

    // ---- stage a (all 16 batch rows; zeros for b >= nb) ----
    {
        int b = tid >> 5, s = tid & 31;
        const ushort* g = At + ((size_t)b * DMODEL + d) * LSEQ + s * 32;
#pragma unroll
        for (int j = 0; j < 4; j++) {       // 4 x 16B = 32 ushorts
            uint4 v = {0u, 0u, 0u, 0u};
            if (b < nb) v = *(const uint4*)(g + 8 * j);
            int byte = (b * 1024 + s * 32 + 8 * j) * 2;
            *(uint4*)((char*)a_lds + (byte ^ (b << 4))) = v;
        }
    }
    // ---- build reversed-shifted k copies for both orders ----
    // kc[o][p][u] = bf16(k_o[1023 - u - p]), zero when index < 0
    for (int idx = tid; idx < 2 * 8 * KCP; idx += 512) {
        int o = idx / (8 * KCP);
        int rem = idx - o * (8 * KCP);
        int pp = rem / KCP;
        int u = rem - pp * KCP;
        int ki = 1023 - u - pp;
        float kv = (ki >= 0) ? kt[((size_t)o * DMODEL + d) * LSEQ + ki] : 0.f;
        kc[idx] = f2bf(kv);
    }
    __syncthreads();

    int p = (7 - lr) & 7;                  // lane parity (m,h-invariant)
    int v0 = 1023 - lr + 8 * lq - p;       // multiple of 8 -> 16B aligned
    int a_base = lr * 2048 + lq * 16;
    int swz = lr << 4;
    const int tis[4] = {w, 31 - w, 8 + w, 23 - w};  // balanced: 132 MFMA/wave

    for (int o = 0; o < 2; o++) {
        f32x4 acc[4][2] = {};
        const char* kb = (const char*)kc + ((size_t)(o * 8 + p) * KCP + v0) * 2;
        for (int m = 0; m < 32; m++) {
            bf16x8 b0 = *(const bf16x8*)(kb - 64 * m);        // h=0
            bf16x8 b1 = *(const bf16x8*)(kb - 64 * m - 32);   // h=1
#pragma unroll
            for (int ii = 0; ii < 4; ii++) {
                if (tis[ii] >= m) {
                    bf16x8 af = *(const bf16x8*)((const char*)a_lds +
                                                 ((a_base + 64 * (tis[ii] - m)) ^ swz));
                    acc[ii][0] = __builtin_amdgcn_mfma_f32_16x16x32_bf16(af, b0, acc[ii][0], 0, 0, 0);
                    acc[ii][1] = __builtin_amdgcn_mfma_f32_16x16x32_bf16(af, b1, acc[ii][1], 0, 0, 0);
                }
            }
        }
        // ---- epilogue: each (b,t) cell read+written by exactly one lane ----
        float db = Db[o * DMODEL + d];
        __syncthreads();  // all MFMA reads of a_lds complete
#pragma unroll
        for (int ii = 0; ii < 4; ii++)
#pragma unroll
            for (int h = 0; h < 2; h++)
#pragma unroll
                for (int r = 0; r < 4; r++) {
                    int t2 = 32 * tis[ii] + 16 * h + lr;
                    int b = lq * 4 + r;
                    int ab = ((b * 1024 + t2) * 2) ^ (b << 4);
                    float a0 = bf2f(*(const ushort*)((const char*)a_lds + ab));
                    float y = acc[ii][h][r] + a0 * db;
                    if (o == 0) {
                        float g = 0.f;
                        if (b < nb) g = bf2f(X1t[((size_t)b * DMODEL + d) * LSEQ + t2]);
                        y *= g;
                    }
                    *(ushort*)((char*)a_lds + ab) = f2bf(y);
                }
        __syncthreads();
    }
    // ---- writeout ----
    {
        int b = tid >> 5, s = tid & 31;
        if (b < nb) {
            ushort* g = V2t + ((size_t)b * DMODEL + d) * LSEQ + s * 32;
#pragma unroll
            for (int j = 0; j < 4; j++) {   // 4 x 16B = 32 ushorts
                int byte = (b * 1024 + s * 32 + 8 * j) * 2;
                uint4 v = *(const uint4*)((const char*)a_lds + (byte ^ (b << 4)));
                *(uint4*)(g + 8 * j) = v;
            }
        }
    }
}

// ---------------------------------------------------------------------------
// Flat fp32 -> bf16 convert (4 elems/thread)
// ---------------------------------------------------------------------------
__global__ void cvt_bf16(const float* __restrict__ in, ushort* __restrict__ out, int n4) {
    int i = blockIdx.x * blockDim.x + threadIdx.x;
    if (i >= n4) return;
    float4 v = *(const float4*)&in[4 * i];
    uint2 pk;
    pk.x = (uint)f2bf(v.x) | ((uint)f2bf(v.y) << 16);
    pk.y = (uint)f2bf(v.z) | ((uint)f2bf(v.w) << 16);
    *(uint2*)&out[4 * i] = pk;
}

// ---------------------------------------------------------------------------
// Transpose + convert: in [R][C] fp32 -> out [C][R] bf16 (single z)
// ---------------------------------------------------------------------------
__global__ void transpose_cvt(const float* __restrict__ in, ushort* __restrict__ out,
                              int R, int C) {
    __shared__ float tile[32][33];
    int c0 = blockIdx.x * 32, r0 = blockIdx.y * 32;
    int tx = threadIdx.x, ty = threadIdx.y;
#pragma unroll
    for (int i = 0; i < 4; i++)
        tile[ty + 8 * i][tx] = in[(size_t)(r0 + ty + 8 * i) * C + c0 + tx];
    __syncthreads();
#pragma unroll
    for (int i = 0; i < 4; i++)
        out[(size_t)(c0 + ty + 8 * i) * R + r0 + tx] = f2bf(tile[tx][ty + 8 * i]);
}

// ---------------------------------------------------------------------------
// Per-batch bf16 transpose: in [b][D][L] -> out [b][L][D]
// ---------------------------------------------------------------------------
__global__ void transpose_b16(const ushort* __restrict__ in, ushort* __restrict__ out) {
    __shared__ ushort tile[32][33];
    int t0 = blockIdx.x * 32, d0 = blockIdx.y * 32, b = blockIdx.z;
    int tx = threadIdx.x, ty = threadIdx.y;
    const ushort* ip = in + (size_t)b * DMODEL * LSEQ;
    ushort* op = out + (size_t)b * LSEQ * DMODEL;
#pragma unroll
    for (int i = 0; i < 4; i++)
        tile[ty + 8 * i][tx] = ip[(size_t)(d0 + ty + 8 * i) * LSEQ + t0 + tx];
    __syncthreads();
#pragma unroll
    for (int i = 0; i < 4; i++)
        op[(size_t)(t0 + ty + 8 * i) * DMODEL + d0 + tx] = tile[tx][ty + 8 * i];
}

// ---------------------------------------------------------------------------
// bfused[n] = b_in[n] + sum_k bp[k] * W_in[k][n]
// ---------------------------------------------------------------------------
__global__ void bias_fuse(const float* __restrict__ bp, const float* __restrict__ W_in,
                          const float* __restrict__ b_in, float* __restrict__ bf) {
    int n = blockIdx.x * blockDim.x + threadIdx.x;
    float s = b_in[n];
    for (int k = 0; k < DMODEL; k++) s += bp[k] * W_in[(size_t)k * D3 + n];
    bf[n] = s;
}

// ---------------------------------------------------------------------------
// Transpose k_filt [2][L][D] fp32 -> kt [2][D][L] fp32
// ---------------------------------------------------------------------------
__global__ void transpose_k(const float* __restrict__ kf, float* __restrict__ kt) {
    __shared__ float tile[32][33];
    int s0 = blockIdx.x * 32, d0 = blockIdx.y * 32, o = blockIdx.z;
    int tx = threadIdx.x, ty = threadIdx.y;
#pragma unroll
    for (int i = 0; i < 4; i++)
        tile[ty + 8 * i][tx] = kf[((size_t)o * LSEQ + s0 + ty + 8 * i) * DMODEL + d0 + tx];
    __syncthreads();
#pragma unroll
    for (int i = 0; i < 4; i++)
        kt[((size_t)o * DMODEL + d0 + ty + 8 * i) * LSEQ + s0 + tx] = tile[tx][ty + 8 * i];
}

// ---------------------------------------------------------------------------
// Depthwise causal 3-tap conv on UC [cf,L,3D] fp32 + gating -> bf16 outputs
// At[b][d][t] = v*x2, X1t[b][d][t] = x1. grid (32, 32, cf), block (32,8)
// ---------------------------------------------------------------------------
__global__ __launch_bounds__(256) void shortconv_gate(const float* __restrict__ UC,
                                                      const float* __restrict__ sw,
                                                      const float* __restrict__ sb,
                                                      ushort* __restrict__ At,
                                                      ushort* __restrict__ X1t) {
    __shared__ float tin[34][33];
    __shared__ float outA[32][33];
    __shared__ float outX[32][33];
    int t0 = blockIdx.x * 32, c0 = blockIdx.y * 32, b = blockIdx.z;
    int tx = threadIdx.x, ty = threadIdx.y;
    float res[3][4];
#pragma unroll
    for (int g = 0; g < 3; g++) {
        int ch = g * DMODEL + c0 + tx;
        __syncthreads();
        for (int r = ty; r < 34; r += 8) {
            int t = t0 + r - 2;
            tin[r][tx] = (t >= 0) ? UC[((size_t)b * LSEQ + t) * D3 + ch] : 0.f;
        }
        __syncthreads();
        float w0 = sw[ch * 3 + 0], w1 = sw[ch * 3 + 1], w2 = sw[ch * 3 + 2], bb = sb[ch];
#pragma unroll
        for (int i = 0; i < 4; i++) {
            int r = ty + 8 * i + 2;
            res[g][i] = w0 * tin[r - 2][tx] + w1 * tin[r - 1][tx] + w2 * tin[r][tx] + bb;
        }
    }
#pragma unroll
    for (int i = 0; i < 4; i++) {
        outA[tx][ty + 8 * i] = res[2][i] * res[1][i];
        outX[tx][ty + 8 * i] = res[0][i];
    }
    __syncthreads();
#pragma unroll
    for (int i = 0; i < 4; i++) {
        int cl = ty + 8 * i;
        size_t o = ((size_t)b * DMODEL + c0 + cl) * LSEQ + t0 + tx;
        At[o] = f2bf(outA[cl][tx]);
        X1t[o] = f2bf(outX[cl][tx]);
    }
}

// ---------------------------------------------------------------------------
extern "C" void kernel_launch(void* const* d_in, const int* in_sizes, int n_in,
                              void* d_out, int out_size, void* d_ws, size_t ws_size,
                              hipStream_t stream) {
    (void)in_sizes; (void)n_in; (void)out_size;
    const float* x    = (const float*)d_in[0];
    const float* Wp   = (const float*)d_in[1];
    const float* bp   = (const float*)d_in[2];
    const float* W_in = (const float*)d_in[3];
    const float* b_in = (const float*)d_in[4];
    const float* sw   = (const float*)d_in[5];
    const float* sb   = (const float*)d_in[6];
    const float* kf   = (const float*)d_in[7];
    const float* Db   = (const float*)d_in[8];
    const float* Wout = (const float*)d_in[9];
    const float* bout = (const float*)d_in[10];
    float* out = (float*)d_out;

    char* ws = (char*)d_ws;
    // Persistent: Wf_t(3145728) bf(16384) kt(8388608) Wout_t(2097152)
    ushort* Wf_t   = (ushort*)(ws);
    float*  bfv    = (float*)(ws + 3145728);
    float*  kt     = (float*)(ws + 3162112);
    ushort* Wout_t = (ushort*)(ws + 11550720);
    const size_t PB = 13647872;

    // per-batch element sizes (bytes)
    const size_t XB = 1048576;    // x_bf bf16
    const size_t ATB = 2097152;   // At bf16
    const size_t X1B = 2097152;   // X1t bf16
    const size_t UCB = 12582912;  // UC fp32
    const size_t V2B = 2097152;   // V2t / V2 bf16

    int cb = 1, cf = 1;
    {
        bool ok = false;
        for (int tcb = 16; tcb >= 1 && !ok; tcb >>= 1) {
            int cfmax = tcb < 8 ? tcb : 8;
            for (int tcf = cfmax; tcf >= 1; tcf >>= 1) {
                size_t ucreg = (size_t)tcf * UCB;
                size_t v2need = (size_t)2 * tcb * V2B;
                if (ucreg < v2need) ucreg = v2need;
                size_t need = PB + (size_t)tcb * (XB + ATB + X1B) + ucreg;
                if (need <= ws_size) { cb = tcb; cf = tcf; ok = true; break; }
            }
        }
    }

    ushort* x_bf = (ushort*)(ws + PB);
    ushort* Atb  = (ushort*)(ws + PB + (size_t)cb * XB);
    ushort* X1tb = (ushort*)(ws + PB + (size_t)cb * (XB + ATB));
    char*   ucrg = ws + PB + (size_t)cb * (XB + ATB + X1B);
    float*  UC   = (float*)ucrg;
    ushort* V2t  = (ushort*)ucrg;
    ushort* V2   = (ushort*)(ucrg + (size_t)cb * V2B);
    // prep scratch aliases the UC region (used before UC is written)
    ushort* W_inT = (ushort*)ucrg;
    ushort* Wp_bf = (ushort*)(ucrg + 6291456);

    // ---- one-time prep ----
    transpose_cvt<<<dim3(96, 32), dim3(32, 8), 0, stream>>>(W_in, W_inT, DMODEL, D3);
    cvt_bf16<<<512, 256, 0, stream>>>(Wp, Wp_bf, DIN * DMODEL / 4);
    gemm_mfma<ushort, false><<<dim3(4, 24), 256, 0, stream>>>(W_inT, Wp_bf, nullptr,
                                                              Wf_t, D3, DIN, DMODEL);
    bias_fuse<<<D3 / 256, 256, 0, stream>>>(bp, W_in, b_in, bfv);
    transpose_cvt<<<dim3(32, 32), dim3(32, 8), 0, stream>>>(Wout, Wout_t, DMODEL, DMODEL);
    transpose_k<<<dim3(32, 32, 2), dim3(32, 8), 0, stream>>>(kf, kt);

    // ---- super-chunks of cb batches ----
    for (int b0 = 0; b0 < BATCH; b0 += cb) {
        cvt_bf16<<<cb * LSEQ * DIN / 1024, 256, 0, stream>>>(
            x + (size_t)b0 * LSEQ * DIN, x_bf, cb * LSEQ * DIN / 4);
        for (int f0 = 0; f0 < cb; f0 += cf) {
            // UC = x_bf @ Wf + bf   [cf*L, 3072] fp32
            gemm_mfma<float, true><<<dim3(24, cf * 8), 256, 0, stream>>>(
                x_bf + (size_t)f0 * LSEQ * DIN, Wf_t, bfv, UC, cf * LSEQ, D3, DIN);
            shortconv_gate<<<dim3(32, 32, cf), dim3(32, 8), 0, stream>>>(
                UC, sw, sb, Atb + (size_t)f0 * DMODEL * LSEQ,
                X1tb + (size_t)f0 * DMODEL * LSEQ);
        }
        // fused long-conv pair (block-Toeplitz MFMA), writes V2t bf16 [b][d][t]
        conv_mfma<<<DMODEL, 512, 0, stream>>>(Atb, X1tb, kt, Db, V2t, cb);
        // V2 [b][t][d] <- V2t [b][d][t]
        transpose_b16<<<dim3(32, 32, cb), dim3(32, 8), 0, stream>>>(V2t, V2);
        // out = V2 @ W_out + b_out
        gemm_mfma<float, true><<<dim3(8, cb * 8), 256, 0, stream>>>(
            V2, Wout_t, bout, out + (size_t)b0 * LSEQ * DMODEL, cb * LSEQ, DMODEL, DMODEL);
    }
}

// Round 6
// 479.019 us; speedup vs baseline: 6.2845x; 1.1636x over previous
//
#include <hip/hip_runtime.h>

#define BATCH 16
#define LSEQ 1024
#define DIN 512
#define DMODEL 1024
#define D3 3072
#define KCP 1064  // padded stride of each reversed-k copy (2128B: all 8 copies distinct 16B phase mod 128B)

typedef __attribute__((ext_vector_type(4))) float f32x4;
typedef __attribute__((ext_vector_type(8))) short bf16x8;

static __device__ __forceinline__ ushort f2bf(float f) {
    uint u = __float_as_uint(f);
    return (ushort)((u + 0x7FFFu + ((u >> 16) & 1u)) >> 16);
}
static __device__ __forceinline__ float bf2f(ushort h) {
    return __uint_as_float(((uint)h) << 16);
}

#define GLD16(ldst, gsrc)                                                        \
    __builtin_amdgcn_global_load_lds(                                            \
        (const __attribute__((address_space(1))) void*)(gsrc),                   \
        (__attribute__((address_space(3))) void*)(ldst), 16, 0, 0)

// ---------------------------------------------------------------------------
// bf16 MFMA GEMM: C[M,N] = A[M,K]bf16 * B (as Bt[N,K]bf16) + bias.
// 128x128 tile, BK=32, 256 threads (4 waves), 4x4 16x16x32 frags per wave.
// ---------------------------------------------------------------------------
template <typename OutT, bool HAS_BIAS>
__global__ __launch_bounds__(256) void gemm_mfma(const ushort* __restrict__ A,
                                                 const ushort* __restrict__ Bt,
                                                 const float* __restrict__ bias,
                                                 OutT* __restrict__ C,
                                                 int M, int N, int K) {
    __shared__ ushort Als[128 * 32];
    __shared__ ushort Bls[128 * 32];
    int n0 = blockIdx.x * 128, m0 = blockIdx.y * 128;
    int t = threadIdx.x;
    int w = t >> 6, l = t & 63;
    int wm = w & 1, wn = w >> 1;
    f32x4 acc[4][4] = {};

    int rowA = t >> 2;
    int kb = (t & 3) * 8;
    const ushort* gA0 = A + (size_t)(m0 + rowA) * K + kb;
    const ushort* gA1 = gA0 + (size_t)64 * K;
    const ushort* gB0 = Bt + (size_t)(n0 + rowA) * K + kb;
    const ushort* gB1 = gB0 + (size_t)64 * K;
    ushort* lA0 = Als + 512 * w;
    ushort* lA1 = Als + 2048 + 512 * w;
    ushort* lB0 = Bls + 512 * w;
    ushort* lB1 = Bls + 2048 + 512 * w;

    int aoff = (wm * 64 + (l & 15)) * 32 + (l >> 4) * 8;
    int boff = (wn * 64 + (l & 15)) * 32 + (l >> 4) * 8;

    for (int k0 = 0; k0 < K; k0 += 32) {
        GLD16(lA0, gA0 + k0);
        GLD16(lA1, gA1 + k0);
        GLD16(lB0, gB0 + k0);
        GLD16(lB1, gB1 + k0);
        __syncthreads();
        bf16x8 af[4], bg[4];
#pragma unroll
        for (int i = 0; i < 4; i++) af[i] = *(const bf16x8*)&Als[aoff + i * 512];
#pragma unroll
        for (int j = 0; j < 4; j++) bg[j] = *(const bf16x8*)&Bls[boff + j * 512];
#pragma unroll
        for (int i = 0; i < 4; i++)
#pragma unroll
            for (int j = 0; j < 4; j++)
                acc[i][j] = __builtin_amdgcn_mfma_f32_16x16x32_bf16(af[i], bg[j],
                                                                    acc[i][j], 0, 0, 0);
        __syncthreads();
    }

#pragma unroll
    for (int j = 0; j < 4; j++) {
        int col = n0 + wn * 64 + 16 * j + (l & 15);
        float bv = HAS_BIAS ? bias[col] : 0.f;
#pragma unroll
        for (int i = 0; i < 4; i++) {
            int row0 = m0 + wm * 64 + 16 * i + (l >> 4) * 4;
#pragma unroll
            for (int r = 0; r < 4; r++) {
                float v = acc[i][j][r] + bv;
                if constexpr (sizeof(OutT) == 2)
                    C[(size_t)(row0 + r) * N + col] = (OutT)f2bf(v);
                else
                    C[(size_t)(row0 + r) * N + col] = (OutT)v;
            }
        }
    }
}

// ---------------------------------------------------------------------------
// Fused long-conv pair via block-Toeplitz MFMA, one workgroup per channel d.
// a(=v*x2) in LDS (bf16, XOR-swizzled); 8 parity-shifted reversed-k copies
// give aligned ds_read_b128 B-fragments: T_m[q][tr] = k[32m+tr-q].
// pass0: y1 = conv_k0(a) + a*D0;  a <- y1 * x1
// pass1: y2 = conv_k1(a) + a*D1;  write V2t[b][d][t] bf16
// NOTE: launch_bounds(512,2) -> 256-VGPR budget. (512,4) forced 64 VGPR and
// spilled the 8 f32x4 accumulators: 204MB scratch writes/dispatch (round 5).
// Accumulators are named registers (no arrays) to forbid scratch demotion.
// ---------------------------------------------------------------------------
__global__ __launch_bounds__(512, 2) void conv_mfma(const ushort* __restrict__ At,
                                                    const ushort* __restrict__ X1t,
                                                    const float* __restrict__ kt,
                                                    const float* __restrict__ Db,
                                                    ushort* __restrict__ V2t, int nb) {
    __shared__ ushort a_lds[16 * 1024];   // 32 KB
    __shared__ ushort kc[2 * 8 * KCP];    // 34 KB
    int d = blockIdx.x;
    int tid = threadIdx.x;
    int w = tid >> 6, l = tid & 63;
    int lr = l & 15, lq = l >> 4;

    // ---- stage a (16 batch rows; zeros for b >= nb) ----
    {
        int b = tid >> 5, s = tid & 31;
        const ushort* g = At + ((size_t)b * DMODEL + d) * LSEQ + s * 32;
#pragma unroll
        for (int j = 0; j < 4; j++) {       // 4 x 16B = 32 ushorts
            uint4 v = {0u, 0u, 0u, 0u};
            if (b < nb) v = *(const uint4*)(g + 8 * j);
            int byte = (b * 1024 + s * 32 + 8 * j) * 2;
            *(uint4*)((char*)a_lds + (byte ^ (b << 4))) = v;
        }
    }
    // ---- build reversed-shifted k copies for both orders ----
    // kc[o][p][u] = bf16(k_o[1023 - u - p]), zero when index < 0
    for (int idx = tid; idx < 2 * 8 * KCP; idx += 512) {
        int o = idx / (8 * KCP);
        int rem = idx - o * (8 * KCP);
        int pp = rem / KCP;
        int u = rem - pp * KCP;
        int ki = 1023 - u - pp;
        float kv = (ki >= 0) ? kt[((size_t)o * DMODEL + d) * LSEQ + ki] : 0.f;
        kc[idx] = f2bf(kv);
    }
    __syncthreads();

    int p = (7 - lr) & 7;                  // lane parity (m,h-invariant)
    int v0 = 1023 - lr + 8 * lq - p;       // multiple of 8 -> 16B aligned
    int a_base = lr * 2048 + lq * 16;
    int swz = lr << 4;
    int ti0 = w, ti1 = 31 - w, ti2 = 8 + w, ti3 = 23 - w;  // 132 MFMA/wave

    for (int o = 0; o < 2; o++) {
        f32x4 a00 = {}, a01 = {}, a10 = {}, a11 = {};
        f32x4 a20 = {}, a21 = {}, a30 = {}, a31 = {};
        const char* kbp = (const char*)kc + ((size_t)(o * 8 + p) * KCP + v0) * 2;
        for (int m = 0; m < 32; m++) {
            bf16x8 b0 = *(const bf16x8*)(kbp - 64 * m);        // h=0
            bf16x8 b1 = *(const bf16x8*)(kbp - 64 * m - 32);   // h=1
#define CSTEP(TI, A0, A1)                                                      \
            if ((TI) >= m) {                                                   \
                bf16x8 af = *(const bf16x8*)((const char*)a_lds +              \
                                             ((a_base + 64 * ((TI) - m)) ^ swz)); \
                A0 = __builtin_amdgcn_mfma_f32_16x16x32_bf16(af, b0, A0, 0, 0, 0); \
                A1 = __builtin_amdgcn_mfma_f32_16x16x32_bf16(af, b1, A1, 0, 0, 0); \
            }
            CSTEP(ti0, a00, a01)
            CSTEP(ti1, a10, a11)
            CSTEP(ti2, a20, a21)
            CSTEP(ti3, a30, a31)
#undef CSTEP
        }
        // ---- epilogue: each (b,t) cell read+written by exactly one lane ----
        float db = Db[o * DMODEL + d];
        __syncthreads();  // all MFMA reads of a_lds complete
#define CEPI(TI, AC, H)                                                        \
        {                                                                      \
            _Pragma("unroll")                                                  \
            for (int r = 0; r < 4; r++) {                                      \
                int t2 = 32 * (TI) + 16 * (H) + lr;                            \
                int b = lq * 4 + r;                                            \
                int ab = ((b * 1024 + t2) * 2) ^ (b << 4);                     \
                float a0v = bf2f(*(const ushort*)((const char*)a_lds + ab));   \
                float y = (AC)[r] + a0v * db;                                  \
                if (o == 0) {                                                  \
                    float g = (b < nb)                                         \
                        ? bf2f(X1t[((size_t)b * DMODEL + d) * LSEQ + t2]) : 0.f; \
                    y *= g;                                                    \
                }                                                              \
                *(ushort*)((char*)a_lds + ab) = f2bf(y);                       \
            }                                                                  \
        }
        CEPI(ti0, a00, 0) CEPI(ti0, a01, 1)
        CEPI(ti1, a10, 0) CEPI(ti1, a11, 1)
        CEPI(ti2, a20, 0) CEPI(ti2, a21, 1)
        CEPI(ti3, a30, 0) CEPI(ti3, a31, 1)
#undef CEPI
        __syncthreads();
    }
    // ---- writeout ----
    {
        int b = tid >> 5, s = tid & 31;
        if (b < nb) {
            ushort* g = V2t + ((size_t)b * DMODEL + d) * LSEQ + s * 32;
#pragma unroll
            for (int j = 0; j < 4; j++) {   // 4 x 16B = 32 ushorts
                int byte = (b * 1024 + s * 32 + 8 * j) * 2;
                uint4 v = *(const uint4*)((const char*)a_lds + (byte ^ (b << 4)));
                *(uint4*)(g + 8 * j) = v;
            }
        }
    }
}

// ---------------------------------------------------------------------------
// Flat fp32 -> bf16 convert (4 elems/thread)
// ---------------------------------------------------------------------------
__global__ void cvt_bf16(const float* __restrict__ in, ushort* __restrict__ out, int n4) {
    int i = blockIdx.x * blockDim.x + threadIdx.x;
    if (i >= n4) return;
    float4 v = *(const float4*)&in[4 * i];
    uint2 pk;
    pk.x = (uint)f2bf(v.x) | ((uint)f2bf(v.y) << 16);
    pk.y = (uint)f2bf(v.z) | ((uint)f2bf(v.w) << 16);
    *(uint2*)&out[4 * i] = pk;
}

// ---------------------------------------------------------------------------
// Transpose + convert: in [R][C] fp32 -> out [C][R] bf16 (single z)
// ---------------------------------------------------------------------------
__global__ void transpose_cvt(const float* __restrict__ in, ushort* __restrict__ out,
                              int R, int C) {
    __shared__ float tile[32][33];
    int c0 = blockIdx.x * 32, r0 = blockIdx.y * 32;
    int tx = threadIdx.x, ty = threadIdx.y;
#pragma unroll
    for (int i = 0; i < 4; i++)
        tile[ty + 8 * i][tx] = in[(size_t)(r0 + ty + 8 * i) * C + c0 + tx];
    __syncthreads();
#pragma unroll
    for (int i = 0; i < 4; i++)
        out[(size_t)(c0 + ty + 8 * i) * R + r0 + tx] = f2bf(tile[tx][ty + 8 * i]);
}

// ---------------------------------------------------------------------------
// Per-batch bf16 transpose: in [b][D][L] -> out [b][L][D]
// ---------------------------------------------------------------------------
__global__ void transpose_b16(const ushort* __restrict__ in, ushort* __restrict__ out) {
    __shared__ ushort tile[32][33];
    int t0 = blockIdx.x * 32, d0 = blockIdx.y * 32, b = blockIdx.z;
    int tx = threadIdx.x, ty = threadIdx.y;
    const ushort* ip = in + (size_t)b * DMODEL * LSEQ;
    ushort* op = out + (size_t)b * LSEQ * DMODEL;
#pragma unroll
    for (int i = 0; i < 4; i++)
        tile[ty + 8 * i][tx] = ip[(size_t)(d0 + ty + 8 * i) * LSEQ + t0 + tx];
    __syncthreads();
#pragma unroll
    for (int i = 0; i < 4; i++)
        op[(size_t)(t0 + ty + 8 * i) * DMODEL + d0 + tx] = tile[tx][ty + 8 * i];
}

// ---------------------------------------------------------------------------
// bfused[n] = b_in[n] + sum_k bp[k] * W_in[k][n]
// ---------------------------------------------------------------------------
__global__ void bias_fuse(const float* __restrict__ bp, const float* __restrict__ W_in,
                          const float* __restrict__ b_in, float* __restrict__ bf) {
    int n = blockIdx.x * blockDim.x + threadIdx.x;
    float s = b_in[n];
    for (int k = 0; k < DMODEL; k++) s += bp[k] * W_in[(size_t)k * D3 + n];
    bf[n] = s;
}

// ---------------------------------------------------------------------------
// Transpose k_filt [2][L][D] fp32 -> kt [2][D][L] fp32
// ---------------------------------------------------------------------------
__global__ void transpose_k(const float* __restrict__ kf, float* __restrict__ kt) {
    __shared__ float tile[32][33];
    int s0 = blockIdx.x * 32, d0 = blockIdx.y * 32, o = blockIdx.z;
    int tx = threadIdx.x, ty = threadIdx.y;
#pragma unroll
    for (int i = 0; i < 4; i++)
        tile[ty + 8 * i][tx] = kf[((size_t)o * LSEQ + s0 + ty + 8 * i) * DMODEL + d0 + tx];
    __syncthreads();
#pragma unroll
    for (int i = 0; i < 4; i++)
        kt[((size_t)o * DMODEL + d0 + ty + 8 * i) * LSEQ + s0 + tx] = tile[tx][ty + 8 * i];
}

// ---------------------------------------------------------------------------
// Depthwise causal 3-tap conv on UC [cf,L,3D] fp32 + gating -> bf16 outputs
// At[b][d][t] = v*x2, X1t[b][d][t] = x1. grid (32, 32, cf), block (32,8)
// ---------------------------------------------------------------------------
__global__ __launch_bounds__(256) void shortconv_gate(const float* __restrict__ UC,
                                                      const float* __restrict__ sw,
                                                      const float* __restrict__ sb,
                                                      ushort* __restrict__ At,
                                                      ushort* __restrict__ X1t) {
    __shared__ float tin[34][33];
    __shared__ float outA[32][33];
    __shared__ float outX[32][33];
    int t0 = blockIdx.x * 32, c0 = blockIdx.y * 32, b = blockIdx.z;
    int tx = threadIdx.x, ty = threadIdx.y;
    float res[3][4];
#pragma unroll
    for (int g = 0; g < 3; g++) {
        int ch = g * DMODEL + c0 + tx;
        __syncthreads();
        for (int r = ty; r < 34; r += 8) {
            int t = t0 + r - 2;
            tin[r][tx] = (t >= 0) ? UC[((size_t)b * LSEQ + t) * D3 + ch] : 0.f;
        }
        __syncthreads();
        float w0 = sw[ch * 3 + 0], w1 = sw[ch * 3 + 1], w2 = sw[ch * 3 + 2], bb = sb[ch];
#pragma unroll
        for (int i = 0; i < 4; i++) {
            int r = ty + 8 * i + 2;
            res[g][i] = w0 * tin[r - 2][tx] + w1 * tin[r - 1][tx] + w2 * tin[r][tx] + bb;
        }
    }
#pragma unroll
    for (int i = 0; i < 4; i++) {
        outA[tx][ty + 8 * i] = res[2][i] * res[1][i];
        outX[tx][ty + 8 * i] = res[0][i];
    }
    __syncthreads();
#pragma unroll
    for (int i = 0; i < 4; i++) {
        int cl = ty + 8 * i;
        size_t o = ((size_t)b * DMODEL + c0 + cl) * LSEQ + t0 + tx;
        At[o] = f2bf(outA[cl][tx]);
        X1t[o] = f2bf(outX[cl][tx]);
    }
}

// ---------------------------------------------------------------------------
extern "C" void kernel_launch(void* const* d_in, const int* in_sizes, int n_in,
                              void* d_out, int out_size, void* d_ws, size_t ws_size,
                              hipStream_t stream) {
    (void)in_sizes; (void)n_in; (void)out_size;
    const float* x    = (const float*)d_in[0];
    const float* Wp   = (const float*)d_in[1];
    const float* bp   = (const float*)d_in[2];
    const float* W_in = (const float*)d_in[3];
    const float* b_in = (const float*)d_in[4];
    const float* sw   = (const float*)d_in[5];
    const float* sb   = (const float*)d_in[6];
    const float* kf   = (const float*)d_in[7];
    const float* Db   = (const float*)d_in[8];
    const float* Wout = (const float*)d_in[9];
    const float* bout = (const float*)d_in[10];
    float* out = (float*)d_out;

    char* ws = (char*)d_ws;
    // Persistent: Wf_t(3145728) bf(16384) kt(8388608) Wout_t(2097152)
    ushort* Wf_t   = (ushort*)(ws);
    float*  bfv    = (float*)(ws + 3145728);
    float*  kt     = (float*)(ws + 3162112);
    ushort* Wout_t = (ushort*)(ws + 11550720);
    const size_t PB = 13647872;

    // per-batch element sizes (bytes)
    const size_t XB = 1048576;    // x_bf bf16
    const size_t ATB = 2097152;   // At bf16
    const size_t X1B = 2097152;   // X1t bf16
    const size_t UCB = 12582912;  // UC fp32
    const size_t V2B = 2097152;   // V2t / V2 bf16

    int cb = 1, cf = 1;
    {
        bool ok = false;
        for (int tcb = 16; tcb >= 1 && !ok; tcb >>= 1) {
            int cfmax = tcb < 8 ? tcb : 8;
            for (int tcf = cfmax; tcf >= 1; tcf >>= 1) {
                size_t ucreg = (size_t)tcf * UCB;
                size_t v2need = (size_t)2 * tcb * V2B;
                if (ucreg < v2need) ucreg = v2need;
                size_t need = PB + (size_t)tcb * (XB + ATB + X1B) + ucreg;
                if (need <= ws_size) { cb = tcb; cf = tcf; ok = true; break; }
            }
        }
    }

    ushort* x_bf = (ushort*)(ws + PB);
    ushort* Atb  = (ushort*)(ws + PB + (size_t)cb * XB);
    ushort* X1tb = (ushort*)(ws + PB + (size_t)cb * (XB + ATB));
    char*   ucrg = ws + PB + (size_t)cb * (XB + ATB + X1B);
    float*  UC   = (float*)ucrg;
    ushort* V2t  = (ushort*)ucrg;
    ushort* V2   = (ushort*)(ucrg + (size_t)cb * V2B);
    // prep scratch aliases the UC region (used before UC is written)
    ushort* W_inT = (ushort*)ucrg;
    ushort* Wp_bf = (ushort*)(ucrg + 6291456);

    // ---- one-time prep ----
    transpose_cvt<<<dim3(96, 32), dim3(32, 8), 0, stream>>>(W_in, W_inT, DMODEL, D3);
    cvt_bf16<<<512, 256, 0, stream>>>(Wp, Wp_bf, DIN * DMODEL / 4);
    gemm_mfma<ushort, false><<<dim3(4, 24), 256, 0, stream>>>(W_inT, Wp_bf, nullptr,
                                                              Wf_t, D3, DIN, DMODEL);
    bias_fuse<<<D3 / 256, 256, 0, stream>>>(bp, W_in, b_in, bfv);
    transpose_cvt<<<dim3(32, 32), dim3(32, 8), 0, stream>>>(Wout, Wout_t, DMODEL, DMODEL);
    transpose_k<<<dim3(32, 32, 2), dim3(32, 8), 0, stream>>>(kf, kt);

    // ---- super-chunks of cb batches ----
    for (int b0 = 0; b0 < BATCH; b0 += cb) {
        cvt_bf16<<<cb * LSEQ * DIN / 1024, 256, 0, stream>>>(
            x + (size_t)b0 * LSEQ * DIN, x_bf, cb * LSEQ * DIN / 4);
        for (int f0 = 0; f0 < cb; f0 += cf) {
            // UC = x_bf @ Wf + bf   [cf*L, 3072] fp32
            gemm_mfma<float, true><<<dim3(24, cf * 8), 256, 0, stream>>>(
                x_bf + (size_t)f0 * LSEQ * DIN, Wf_t, bfv, UC, cf * LSEQ, D3, DIN);
            shortconv_gate<<<dim3(32, 32, cf), dim3(32, 8), 0, stream>>>(
                UC, sw, sb, Atb + (size_t)f0 * DMODEL * LSEQ,
                X1tb + (size_t)f0 * DMODEL * LSEQ);
        }
        // fused long-conv pair (block-Toeplitz MFMA), writes V2t bf16 [b][d][t]
        conv_mfma<<<DMODEL, 512, 0, stream>>>(Atb, X1tb, kt, Db, V2t, cb);
        // V2 [b][t][d] <- V2t [b][d][t]
        transpose_b16<<<dim3(32, 32, cb), dim3(32, 8), 0, stream>>>(V2t, V2);
        // out = V2 @ W_out + b_out
        gemm_mfma<float, true><<<dim3(8, cb * 8), 256, 0, stream>>>(
            V2, Wout_t, bout, out + (size_t)b0 * LSEQ * DMODEL, cb * LSEQ, DMODEL, DMODEL);
    }
}

// Round 7
// 454.278 us; speedup vs baseline: 6.6268x; 1.0545x over previous
//
#include <hip/hip_runtime.h>

#define BATCH 16
#define LSEQ 1024
#define DIN 512
#define DMODEL 1024
#define D3 3072
#define KCP 1064  // padded stride of each reversed-k copy (2128B: all 8 copies distinct 16B phase mod 128B)

typedef __attribute__((ext_vector_type(4))) float f32x4;
typedef __attribute__((ext_vector_type(8))) short bf16x8;

static __device__ __forceinline__ ushort f2bf(float f) {
    uint u = __float_as_uint(f);
    return (ushort)((u + 0x7FFFu + ((u >> 16) & 1u)) >> 16);
}
static __device__ __forceinline__ float bf2f(ushort h) {
    return __uint_as_float(((uint)h) << 16);
}

#define GLD16(ldst, gsrc)                                                        \
    __builtin_amdgcn_global_load_lds(                                            \
        (const __attribute__((address_space(1))) void*)(gsrc),                   \
        (__attribute__((address_space(3))) void*)(ldst), 16, 0, 0)

// ---------------------------------------------------------------------------
// bf16 MFMA GEMM: C[M,N] = A[M,K]bf16 * B (as Bt[N,K]bf16) + bias.
// 128x128 tile, BK=32, 256 threads (4 waves), 4x4 16x16x32 frags per wave.
// 2-phase double-buffered staging (issue next slab's global_load_lds BEFORE
// computing current; single barrier per K-step; compiler's auto vmcnt-drain
// before s_barrier gives the wait semantics).
// ---------------------------------------------------------------------------
template <typename OutT, bool HAS_BIAS>
__global__ __launch_bounds__(256) void gemm_mfma(const ushort* __restrict__ A,
                                                 const ushort* __restrict__ Bt,
                                                 const float* __restrict__ bias,
                                                 OutT* __restrict__ C,
                                                 int M, int N, int K) {
    __shared__ ushort Als[2][128 * 32];
    __shared__ ushort Bls[2][128 * 32];
    int n0 = blockIdx.x * 128, m0 = blockIdx.y * 128;
    int t = threadIdx.x;
    int w = t >> 6, l = t & 63;
    int wm = w & 1, wn = w >> 1;
    f32x4 acc[4][4] = {};

    int rowA = t >> 2;
    int kb = (t & 3) * 8;
    const ushort* gA0 = A + (size_t)(m0 + rowA) * K + kb;
    const ushort* gA1 = gA0 + (size_t)64 * K;
    const ushort* gB0 = Bt + (size_t)(n0 + rowA) * K + kb;
    const ushort* gB1 = gB0 + (size_t)64 * K;
    int so = 512 * w;  // wave-uniform slot offset

    int aoff = (wm * 64 + (l & 15)) * 32 + (l >> 4) * 8;
    int boff = (wn * 64 + (l & 15)) * 32 + (l >> 4) * 8;

    // prologue: stage slab 0 into buffer 0
    GLD16(&Als[0][so], gA0);
    GLD16(&Als[0][2048 + so], gA1);
    GLD16(&Bls[0][so], gB0);
    GLD16(&Bls[0][2048 + so], gB1);
    __syncthreads();

    int cur = 0;
    for (int k0 = 0; k0 < K; k0 += 32) {
        int nxt = cur ^ 1;
        if (k0 + 32 < K) {  // issue next-slab loads; they fly over the MFMAs
            GLD16(&Als[nxt][so], gA0 + k0 + 32);
            GLD16(&Als[nxt][2048 + so], gA1 + k0 + 32);
            GLD16(&Bls[nxt][so], gB0 + k0 + 32);
            GLD16(&Bls[nxt][2048 + so], gB1 + k0 + 32);
        }
        bf16x8 af[4], bg[4];
#pragma unroll
        for (int i = 0; i < 4; i++) af[i] = *(const bf16x8*)&Als[cur][aoff + i * 512];
#pragma unroll
        for (int j = 0; j < 4; j++) bg[j] = *(const bf16x8*)&Bls[cur][boff + j * 512];
#pragma unroll
        for (int i = 0; i < 4; i++)
#pragma unroll
            for (int j = 0; j < 4; j++)
                acc[i][j] = __builtin_amdgcn_mfma_f32_16x16x32_bf16(af[i], bg[j],
                                                                    acc[i][j], 0, 0, 0);
        __syncthreads();  // next buffer landed; everyone done reading cur
        cur = nxt;
    }

#pragma unroll
    for (int j = 0; j < 4; j++) {
        int col = n0 + wn * 64 + 16 * j + (l & 15);
        float bv = HAS_BIAS ? bias[col] : 0.f;
#pragma unroll
        for (int i = 0; i < 4; i++) {
            int row0 = m0 + wm * 64 + 16 * i + (l >> 4) * 4;
#pragma unroll
            for (int r = 0; r < 4; r++) {
                float v = acc[i][j][r] + bv;
                if constexpr (sizeof(OutT) == 2)
                    C[(size_t)(row0 + r) * N + col] = (OutT)f2bf(v);
                else
                    C[(size_t)(row0 + r) * N + col] = (OutT)v;
            }
        }
    }
}

// ---------------------------------------------------------------------------
// Fused long-conv pair via block-Toeplitz MFMA, one workgroup per channel d.
// a(=v*x2) in LDS (bf16, XOR-swizzled); 8 parity-shifted reversed-k copies
// (rebuilt per pass, 17KB -> LDS 49.8KB -> 3 blocks/CU) give aligned
// ds_read_b128 B-fragments: T_m[q][tr] = k[32m+tr-q].
// pass0: y1 = conv_k0(a) + a*D0;  a <- y1 * x1 (gate prefetched to regs)
// pass1: y2 = conv_k1(a) + a*D1;  write V2t[b][d][t] bf16
// launch_bounds(512,2): (512,4) forced 64 VGPR and spilled (round 5).
// ---------------------------------------------------------------------------
__global__ __launch_bounds__(512, 2) void conv_mfma(const ushort* __restrict__ At,
                                                    const ushort* __restrict__ X1t,
                                                    const float* __restrict__ kt,
                                                    const float* __restrict__ Db,
                                                    ushort* __restrict__ V2t, int nb) {
    __shared__ ushort a_lds[16 * 1024];   // 32 KB
    __shared__ ushort kc[8 * KCP];        // 17 KB, rebuilt per pass
    int d = blockIdx.x;
    int tid = threadIdx.x;
    int w = tid >> 6, l = tid & 63;
    int lr = l & 15, lq = l >> 4;

    // ---- stage a (16 batch rows; zeros for b >= nb) ----
    {
        int b = tid >> 5, s = tid & 31;
        const ushort* g = At + ((size_t)b * DMODEL + d) * LSEQ + s * 32;
#pragma unroll
        for (int j = 0; j < 4; j++) {       // 4 x 16B = 32 ushorts
            uint4 v = {0u, 0u, 0u, 0u};
            if (b < nb) v = *(const uint4*)(g + 8 * j);
            int byte = (b * 1024 + s * 32 + 8 * j) * 2;
            *(uint4*)((char*)a_lds + (byte ^ (b << 4))) = v;
        }
    }

    int p = (7 - lr) & 7;                  // lane parity (m,h-invariant)
    int v0 = 1023 - lr + 8 * lq - p;       // multiple of 8 -> 16B aligned
    int a_base = lr * 2048 + lq * 16;
    int swz = lr << 4;
    const int tis[4] = {w, 31 - w, 8 + w, 23 - w};  // 132 MFMA/wave/pass
    int ti0 = tis[0], ti1 = tis[1], ti2 = tis[2], ti3 = tis[3];

    // ---- prefetch gate x1 for the o==0 epilogue (issue-early, T14) ----
    ushort gpre[4][2][4];
#pragma unroll
    for (int ii = 0; ii < 4; ii++)
#pragma unroll
        for (int h = 0; h < 2; h++)
#pragma unroll
            for (int r = 0; r < 4; r++) {
                int b = lq * 4 + r;
                int t2 = 32 * tis[ii] + 16 * h + lr;
                gpre[ii][h][r] = (b < nb)
                    ? X1t[((size_t)b * DMODEL + d) * LSEQ + t2] : (ushort)0;
            }

    for (int o = 0; o < 2; o++) {
        // ---- build reversed-shifted k copies for this order ----
        // kc[p][u] = bf16(k_o[1023 - u - p]), zero when index < 0
        const float* krow = kt + ((size_t)o * DMODEL + d) * LSEQ;
        for (int idx = tid; idx < 8 * KCP; idx += 512) {
            int pp = idx / KCP;
            int u = idx - pp * KCP;
            int ki = 1023 - u - pp;
            kc[idx] = f2bf((ki >= 0) ? krow[ki] : 0.f);
        }
        __syncthreads();   // kc ready; prior a_lds writes visible

        f32x4 a00 = {}, a01 = {}, a10 = {}, a11 = {};
        f32x4 a20 = {}, a21 = {}, a30 = {}, a31 = {};
        const char* kbp = (const char*)kc + ((size_t)p * KCP + v0) * 2;
        for (int m = 0; m < 32; m++) {
            bf16x8 b0 = *(const bf16x8*)(kbp - 64 * m);        // h=0
            bf16x8 b1 = *(const bf16x8*)(kbp - 64 * m - 32);   // h=1
            __builtin_amdgcn_s_setprio(1);
#define CSTEP(TI, A0, A1)                                                      \
            if ((TI) >= m) {                                                   \
                bf16x8 af = *(const bf16x8*)((const char*)a_lds +              \
                                             ((a_base + 64 * ((TI) - m)) ^ swz)); \
                A0 = __builtin_amdgcn_mfma_f32_16x16x32_bf16(af, b0, A0, 0, 0, 0); \
                A1 = __builtin_amdgcn_mfma_f32_16x16x32_bf16(af, b1, A1, 0, 0, 0); \
            }
            CSTEP(ti0, a00, a01)
            CSTEP(ti1, a10, a11)
            CSTEP(ti2, a20, a21)
            CSTEP(ti3, a30, a31)
#undef CSTEP
            __builtin_amdgcn_s_setprio(0);
        }
        // ---- epilogue: each (b,t) cell read+written by exactly one lane ----
        float db = Db[o * DMODEL + d];
        __syncthreads();  // all MFMA reads of a_lds and kc complete
#define CEPI(II, TI, AC, H)                                                    \
        {                                                                      \
            _Pragma("unroll")                                                  \
            for (int r = 0; r < 4; r++) {                                      \
                int t2 = 32 * (TI) + 16 * (H) + lr;                            \
                int b = lq * 4 + r;                                            \
                int ab = ((b * 1024 + t2) * 2) ^ (b << 4);                     \
                float a0v = bf2f(*(const ushort*)((const char*)a_lds + ab));   \
                float y = (AC)[r] + a0v * db;                                  \
                if (o == 0) y *= bf2f(gpre[II][H][r]);                         \
                *(ushort*)((char*)a_lds + ab) = f2bf(y);                       \
            }                                                                  \
        }
        CEPI(0, ti0, a00, 0) CEPI(0, ti0, a01, 1)
        CEPI(1, ti1, a10, 0) CEPI(1, ti1, a11, 1)
        CEPI(2, ti2, a20, 0) CEPI(2, ti2, a21, 1)
        CEPI(3, ti3, a30, 0) CEPI(3, ti3, a31, 1)
#undef CEPI
        // no barrier here: next pass's kc build touches kc only (reads done),
        // and its pre-mfma barrier publishes the epilogue's a_lds writes.
    }
    __syncthreads();  // publish o=1 epilogue writes for the writeout
    // ---- writeout ----
    {
        int b = tid >> 5, s = tid & 31;
        if (b < nb) {
            ushort* g = V2t + ((size_t)b * DMODEL + d) * LSEQ + s * 32;
#pragma unroll
            for (int j = 0; j < 4; j++) {   // 4 x 16B = 32 ushorts
                int byte = (b * 1024 + s * 32 + 8 * j) * 2;
                uint4 v = *(const uint4*)((const char*)a_lds + (byte ^ (b << 4)));
                *(uint4*)(g + 8 * j) = v;
            }
        }
    }
}

// ---------------------------------------------------------------------------
// Flat fp32 -> bf16 convert (4 elems/thread)
// ---------------------------------------------------------------------------
__global__ void cvt_bf16(const float* __restrict__ in, ushort* __restrict__ out, int n4) {
    int i = blockIdx.x * blockDim.x + threadIdx.x;
    if (i >= n4) return;
    float4 v = *(const float4*)&in[4 * i];
    uint2 pk;
    pk.x = (uint)f2bf(v.x) | ((uint)f2bf(v.y) << 16);
    pk.y = (uint)f2bf(v.z) | ((uint)f2bf(v.w) << 16);
    *(uint2*)&out[4 * i] = pk;
}

// ---------------------------------------------------------------------------
// Transpose + convert: in [R][C] fp32 -> out [C][R] bf16 (single z)
// ---------------------------------------------------------------------------
__global__ void transpose_cvt(const float* __restrict__ in, ushort* __restrict__ out,
                              int R, int C) {
    __shared__ float tile[32][33];
    int c0 = blockIdx.x * 32, r0 = blockIdx.y * 32;
    int tx = threadIdx.x, ty = threadIdx.y;
#pragma unroll
    for (int i = 0; i < 4; i++)
        tile[ty + 8 * i][tx] = in[(size_t)(r0 + ty + 8 * i) * C + c0 + tx];
    __syncthreads();
#pragma unroll
    for (int i = 0; i < 4; i++)
        out[(size_t)(c0 + ty + 8 * i) * R + r0 + tx] = f2bf(tile[tx][ty + 8 * i]);
}

// ---------------------------------------------------------------------------
// Per-batch bf16 transpose: in [b][D][L] -> out [b][L][D]
// ---------------------------------------------------------------------------
__global__ void transpose_b16(const ushort* __restrict__ in, ushort* __restrict__ out) {
    __shared__ ushort tile[32][33];
    int t0 = blockIdx.x * 32, d0 = blockIdx.y * 32, b = blockIdx.z;
    int tx = threadIdx.x, ty = threadIdx.y;
    const ushort* ip = in + (size_t)b * DMODEL * LSEQ;
    ushort* op = out + (size_t)b * LSEQ * DMODEL;
#pragma unroll
    for (int i = 0; i < 4; i++)
        tile[ty + 8 * i][tx] = ip[(size_t)(d0 + ty + 8 * i) * LSEQ + t0 + tx];
    __syncthreads();
#pragma unroll
    for (int i = 0; i < 4; i++)
        op[(size_t)(t0 + ty + 8 * i) * DMODEL + d0 + tx] = tile[tx][ty + 8 * i];
}

// ---------------------------------------------------------------------------
// bfused[n] = b_in[n] + sum_k bp[k] * W_in[k][n]
// ---------------------------------------------------------------------------
__global__ void bias_fuse(const float* __restrict__ bp, const float* __restrict__ W_in,
                          const float* __restrict__ b_in, float* __restrict__ bf) {
    int n = blockIdx.x * blockDim.x + threadIdx.x;
    float s = b_in[n];
    for (int k = 0; k < DMODEL; k++) s += bp[k] * W_in[(size_t)k * D3 + n];
    bf[n] = s;
}

// ---------------------------------------------------------------------------
// Transpose k_filt [2][L][D] fp32 -> kt [2][D][L] fp32
// ---------------------------------------------------------------------------
__global__ void transpose_k(const float* __restrict__ kf, float* __restrict__ kt) {
    __shared__ float tile[32][33];
    int s0 = blockIdx.x * 32, d0 = blockIdx.y * 32, o = blockIdx.z;
    int tx = threadIdx.x, ty = threadIdx.y;
#pragma unroll
    for (int i = 0; i < 4; i++)
        tile[ty + 8 * i][tx] = kf[((size_t)o * LSEQ + s0 + ty + 8 * i) * DMODEL + d0 + tx];
    __syncthreads();
#pragma unroll
    for (int i = 0; i < 4; i++)
        kt[((size_t)o * DMODEL + d0 + ty + 8 * i) * LSEQ + s0 + tx] = tile[tx][ty + 8 * i];
}

// ---------------------------------------------------------------------------
// Depthwise causal 3-tap conv on UC [cf,L,3D] bf16 + gating -> bf16 outputs
// At[b][d][t] = v*x2, X1t[b][d][t] = x1. grid (32, 32, cf), block (32,8)
// ---------------------------------------------------------------------------
__global__ __launch_bounds__(256) void shortconv_gate(const ushort* __restrict__ UC,
                                                      const float* __restrict__ sw,
                                                      const float* __restrict__ sb,
                                                      ushort* __restrict__ At,
                                                      ushort* __restrict__ X1t) {
    __shared__ float tin[34][33];
    __shared__ float outA[32][33];
    __shared__ float outX[32][33];
    int t0 = blockIdx.x * 32, c0 = blockIdx.y * 32, b = blockIdx.z;
    int tx = threadIdx.x, ty = threadIdx.y;
    float res[3][4];
#pragma unroll
    for (int g = 0; g < 3; g++) {
        int ch = g * DMODEL + c0 + tx;
        __syncthreads();
        for (int r = ty; r < 34; r += 8) {
            int t = t0 + r - 2;
            tin[r][tx] = (t >= 0) ? bf2f(UC[((size_t)b * LSEQ + t) * D3 + ch]) : 0.f;
        }
        __syncthreads();
        float w0 = sw[ch * 3 + 0], w1 = sw[ch * 3 + 1], w2 = sw[ch * 3 + 2], bb = sb[ch];
#pragma unroll
        for (int i = 0; i < 4; i++) {
            int r = ty + 8 * i + 2;
            res[g][i] = w0 * tin[r - 2][tx] + w1 * tin[r - 1][tx] + w2 * tin[r][tx] + bb;
        }
    }
#pragma unroll
    for (int i = 0; i < 4; i++) {
        outA[tx][ty + 8 * i] = res[2][i] * res[1][i];
        outX[tx][ty + 8 * i] = res[0][i];
    }
    __syncthreads();
#pragma unroll
    for (int i = 0; i < 4; i++) {
        int cl = ty + 8 * i;
        size_t o = ((size_t)b * DMODEL + c0 + cl) * LSEQ + t0 + tx;
        At[o] = f2bf(outA[cl][tx]);
        X1t[o] = f2bf(outX[cl][tx]);
    }
}

// ---------------------------------------------------------------------------
extern "C" void kernel_launch(void* const* d_in, const int* in_sizes, int n_in,
                              void* d_out, int out_size, void* d_ws, size_t ws_size,
                              hipStream_t stream) {
    (void)in_sizes; (void)n_in; (void)out_size;
    const float* x    = (const float*)d_in[0];
    const float* Wp   = (const float*)d_in[1];
    const float* bp   = (const float*)d_in[2];
    const float* W_in = (const float*)d_in[3];
    const float* b_in = (const float*)d_in[4];
    const float* sw   = (const float*)d_in[5];
    const float* sb   = (const float*)d_in[6];
    const float* kf   = (const float*)d_in[7];
    const float* Db   = (const float*)d_in[8];
    const float* Wout = (const float*)d_in[9];
    const float* bout = (const float*)d_in[10];
    float* out = (float*)d_out;

    char* ws = (char*)d_ws;
    // Persistent: Wf_t(3145728) bf(16384) kt(8388608) Wout_t(2097152)
    ushort* Wf_t   = (ushort*)(ws);
    float*  bfv    = (float*)(ws + 3145728);
    float*  kt     = (float*)(ws + 3162112);
    ushort* Wout_t = (ushort*)(ws + 11550720);
    const size_t PB = 13647872;

    // per-batch element sizes (bytes)
    const size_t XB  = 1048576;   // x_bf bf16
    const size_t ATB = 2097152;   // At bf16
    const size_t X1B = 2097152;   // X1t bf16
    const size_t UCB = 6291456;   // UC bf16 (1024*3072*2)
    const size_t V2B = 2097152;   // V2t / V2 bf16
    const size_t PREPB = 7340032; // W_inT + Wp_bf prep scratch floor

    int cb = 1, cf = 1;
    {
        bool ok = false;
        for (int tcb = 16; tcb >= 1 && !ok; tcb >>= 1) {
            for (int tcf = tcb; tcf >= 1; tcf >>= 1) {
                size_t ucreg = (size_t)tcf * UCB;
                size_t v2need = (size_t)2 * tcb * V2B;
                if (ucreg < v2need) ucreg = v2need;
                if (ucreg < PREPB) ucreg = PREPB;
                size_t need = PB + (size_t)tcb * (XB + ATB + X1B) + ucreg;
                if (need <= ws_size) { cb = tcb; cf = tcf; ok = true; break; }
            }
        }
    }

    ushort* x_bf = (ushort*)(ws + PB);
    ushort* Atb  = (ushort*)(ws + PB + (size_t)cb * XB);
    ushort* X1tb = (ushort*)(ws + PB + (size_t)cb * (XB + ATB));
    char*   ucrg = ws + PB + (size_t)cb * (XB + ATB + X1B);
    ushort* UC   = (ushort*)ucrg;
    ushort* V2t  = (ushort*)ucrg;                         // UC dead by conv time
    ushort* V2   = (ushort*)(ucrg + (size_t)cb * V2B);
    // prep scratch aliases the UC region (used before UC is written)
    ushort* W_inT = (ushort*)ucrg;
    ushort* Wp_bf = (ushort*)(ucrg + 6291456);

    // ---- one-time prep ----
    transpose_cvt<<<dim3(96, 32), dim3(32, 8), 0, stream>>>(W_in, W_inT, DMODEL, D3);
    cvt_bf16<<<512, 256, 0, stream>>>(Wp, Wp_bf, DIN * DMODEL / 4);
    gemm_mfma<ushort, false><<<dim3(4, 24), 256, 0, stream>>>(W_inT, Wp_bf, nullptr,
                                                              Wf_t, D3, DIN, DMODEL);
    bias_fuse<<<D3 / 256, 256, 0, stream>>>(bp, W_in, b_in, bfv);
    transpose_cvt<<<dim3(32, 32), dim3(32, 8), 0, stream>>>(Wout, Wout_t, DMODEL, DMODEL);
    transpose_k<<<dim3(32, 32, 2), dim3(32, 8), 0, stream>>>(kf, kt);

    // ---- super-chunks of cb batches ----
    for (int b0 = 0; b0 < BATCH; b0 += cb) {
        cvt_bf16<<<cb * LSEQ * DIN / 1024, 256, 0, stream>>>(
            x + (size_t)b0 * LSEQ * DIN, x_bf, cb * LSEQ * DIN / 4);
        for (int f0 = 0; f0 < cb; f0 += cf) {
            // UC = x_bf @ Wf + bf   [cf*L, 3072] bf16
            gemm_mfma<ushort, true><<<dim3(24, cf * 8), 256, 0, stream>>>(
                x_bf + (size_t)f0 * LSEQ * DIN, Wf_t, bfv, UC, cf * LSEQ, D3, DIN);
            shortconv_gate<<<dim3(32, 32, cf), dim3(32, 8), 0, stream>>>(
                UC, sw, sb, Atb + (size_t)f0 * DMODEL * LSEQ,
                X1tb + (size_t)f0 * DMODEL * LSEQ);
        }
        // fused long-conv pair (block-Toeplitz MFMA), writes V2t bf16 [b][d][t]
        conv_mfma<<<DMODEL, 512, 0, stream>>>(Atb, X1tb, kt, Db, V2t, cb);
        // V2 [b][t][d] <- V2t [b][d][t]
        transpose_b16<<<dim3(32, 32, cb), dim3(32, 8), 0, stream>>>(V2t, V2);
        // out = V2 @ W_out + b_out
        gemm_mfma<float, true><<<dim3(8, cb * 8), 256, 0, stream>>>(
            V2, Wout_t, bout, out + (size_t)b0 * LSEQ * DMODEL, cb * LSEQ, DMODEL, DMODEL);
    }
}